// Round 14
// baseline (315.252 us; speedup 1.0000x reference)
//
#include <hip/hip_runtime.h>
#include <hip/hip_bf16.h>

// ---------------------------------------------------------------------------
// DAWN block on MI355X.  Round 14:
//  - fa: T3-minimum single-barrier double-buffered LDS (KVBLK=64, 40KB LDS,
//    4 blocks/CU, XOR-swizzled unpadded tiles, balanced R5 map 66 tiles/CU).
//  - restore GEMM -> legacy 128^2 kernel (768 blocks = 3/CU balanced).
//  - wsf/ws2 reverted to R12 high-grid scalar forms (R13 regression).
//  - feature/W_O/know-f GEMMs unchanged (gemm256 single-phase).
// ---------------------------------------------------------------------------

typedef __bf16 bf16_t;
typedef __bf16 bf16x4 __attribute__((ext_vector_type(4)));
typedef __bf16 bf16x8 __attribute__((ext_vector_type(8)));
typedef float f32x4 __attribute__((ext_vector_type(4)));

#define B_DIM 2
#define S_LEN 2048
#define D_DIM 1024
#define H_NUM 16
#define DH 64
#define N_NEU 8
#define R_DIM 256
#define KR_DIM 128
#define ROWS (B_DIM * S_LEN)   // 4096

static __device__ __forceinline__ void gl_lds16(const void* g, void* l)
{
    __builtin_amdgcn_global_load_lds(
        (__attribute__((address_space(1))) void*)(g),
        (__attribute__((address_space(3))) void*)(l), 16, 0, 0);
}

// ---------------------------------------------------------------------------
// Batched transpose-cast: in[z][I][J] f32 -> out[z][J][I] bf16.  block (32,8)
// ---------------------------------------------------------------------------
__global__ __launch_bounds__(256)
void tcast_kernel(const float* __restrict__ in, bf16_t* __restrict__ out, int I, int J)
{
    __shared__ float t[32][33];
    const int bJ = blockIdx.x * 32, bI = blockIdx.y * 32;
    const size_t boff = (size_t)blockIdx.z * I * J;
    const int tx = threadIdx.x, ty = threadIdx.y;
#pragma unroll
    for (int i = 0; i < 4; i++)
        t[ty * 4 + i][tx] = in[boff + (size_t)(bI + ty * 4 + i) * J + bJ + tx];
    __syncthreads();
#pragma unroll
    for (int i = 0; i < 4; i++)
        out[boff + (size_t)(bJ + ty * 4 + i) * I + bI + tx] = (bf16_t)t[tx][ty * 4 + i];
}

// bf16 transpose: in[z][I][J] -> out[z][J][I].  block (32,8)
__global__ __launch_bounds__(256)
void tbf_kernel(const bf16_t* __restrict__ in, bf16_t* __restrict__ out, int I, int J)
{
    __shared__ bf16_t t[32][33];
    const int bJ = blockIdx.x * 32, bI = blockIdx.y * 32;
    const size_t boff = (size_t)blockIdx.z * I * J;
    const int tx = threadIdx.x, ty = threadIdx.y;
#pragma unroll
    for (int i = 0; i < 4; i++)
        t[ty * 4 + i][tx] = in[boff + (size_t)(bI + ty * 4 + i) * J + bJ + tx];
    __syncthreads();
#pragma unroll
    for (int i = 0; i < 4; i++)
        out[boff + (size_t)(bJ + ty * 4 + i) * I + bI + tx] = t[tx][ty * 4 + i];
}

// plain cast fp32 -> bf16 (vectorized by 4)
__global__ __launch_bounds__(256)
void cast_kernel(const float* __restrict__ in, bf16_t* __restrict__ out, int n4)
{
    int i = blockIdx.x * 256 + threadIdx.x;
    if (i < n4) {
        float4 v = ((const float4*)in)[i];
        bf16_t* op = out + (size_t)i * 4;
        op[0] = (bf16_t)v.x; op[1] = (bf16_t)v.y; op[2] = (bf16_t)v.z; op[3] = (bf16_t)v.w;
    }
}

// ---------------------------------------------------------------------------
// LayerNorm over D=1024, one row per block. fp32 in, bf16 out.
// ---------------------------------------------------------------------------
__global__ __launch_bounds__(256)
void ln_kernel(const float* __restrict__ x, const float* __restrict__ g,
               const float* __restrict__ beta, bf16_t* __restrict__ out)
{
    __shared__ float red[4];
    const int row = blockIdx.x;
    const int tid = threadIdx.x;
    float4 v = *(const float4*)&x[(size_t)row * D_DIM + tid * 4];

    float s = v.x + v.y + v.z + v.w;
#pragma unroll
    for (int o = 32; o; o >>= 1) s += __shfl_down(s, o);
    if ((tid & 63) == 0) red[tid >> 6] = s;
    __syncthreads();
    float mean = (red[0] + red[1] + red[2] + red[3]) * (1.f / D_DIM);
    __syncthreads();

    float dx = v.x - mean, dy = v.y - mean, dz = v.z - mean, dw = v.w - mean;
    float q = dx * dx + dy * dy + dz * dz + dw * dw;
#pragma unroll
    for (int o = 32; o; o >>= 1) q += __shfl_down(q, o);
    if ((tid & 63) == 0) red[tid >> 6] = q;
    __syncthreads();
    float var = (red[0] + red[1] + red[2] + red[3]) * (1.f / D_DIM);
    float rstd = rsqrtf(var + 1e-5f);

    float4 gv = *(const float4*)&g[tid * 4];
    float4 bv = *(const float4*)&beta[tid * 4];
    bf16_t* op = out + (size_t)row * D_DIM + tid * 4;
    op[0] = (bf16_t)(dx * rstd * gv.x + bv.x);
    op[1] = (bf16_t)(dy * rstd * gv.y + bv.y);
    op[2] = (bf16_t)(dz * rstd * gv.z + bv.z);
    op[3] = (bf16_t)(dw * rstd * gv.w + bv.w);
}

// ---------------------------------------------------------------------------
// LN2 with fused split-K reduce (bf16 partials) + residual.
// ---------------------------------------------------------------------------
__global__ __launch_bounds__(256)
void ln2x_kernel(const float* __restrict__ x, const bf16_t* __restrict__ P0,
                 const bf16_t* __restrict__ P1, const float* __restrict__ g,
                 const float* __restrict__ beta, float* __restrict__ outf,
                 bf16_t* __restrict__ outn)
{
    __shared__ float red[4];
    const int row = blockIdx.x;
    const int tid = threadIdx.x;
    const size_t base = (size_t)row * D_DIM + tid * 4;
    float4 v  = *(const float4*)&x[base];
    bf16x4 p0 = *(const bf16x4*)&P0[base];
    bf16x4 p1 = *(const bf16x4*)&P1[base];
    v.x += (float)p0[0] + (float)p1[0];
    v.y += (float)p0[1] + (float)p1[1];
    v.z += (float)p0[2] + (float)p1[2];
    v.w += (float)p0[3] + (float)p1[3];
    *(float4*)&outf[base] = v;

    float s = v.x + v.y + v.z + v.w;
#pragma unroll
    for (int o = 32; o; o >>= 1) s += __shfl_down(s, o);
    if ((tid & 63) == 0) red[tid >> 6] = s;
    __syncthreads();
    float mean = (red[0] + red[1] + red[2] + red[3]) * (1.f / D_DIM);
    __syncthreads();

    float dx = v.x - mean, dy = v.y - mean, dz = v.z - mean, dw = v.w - mean;
    float q = dx * dx + dy * dy + dz * dz + dw * dw;
#pragma unroll
    for (int o = 32; o; o >>= 1) q += __shfl_down(q, o);
    if ((tid & 63) == 0) red[tid >> 6] = q;
    __syncthreads();
    float var = (red[0] + red[1] + red[2] + red[3]) * (1.f / D_DIM);
    float rstd = rsqrtf(var + 1e-5f);

    float4 gv = *(const float4*)&g[tid * 4];
    float4 bv = *(const float4*)&beta[tid * 4];
    bf16_t* op = outn + base;
    op[0] = (bf16_t)(dx * rstd * gv.x + bv.x);
    op[1] = (bf16_t)(dy * rstd * gv.y + bv.y);
    op[2] = (bf16_t)(dz * rstd * gv.z + bv.z);
    op[3] = (bf16_t)(dw * rstd * gv.w + bv.w);
}

// ---------------------------------------------------------------------------
// Fused weighted-sum for Q/K/V (R12 form: 1 row/block, 4096 blocks).
// ---------------------------------------------------------------------------
__global__ __launch_bounds__(256)
void wsf_kernel(const bf16_t* __restrict__ y,
                const float* __restrict__ wfQ, const float* __restrict__ wrQ,
                const float* __restrict__ wfK, const float* __restrict__ wrK,
                const float* __restrict__ wfV, const float* __restrict__ wrV,
                bf16_t* __restrict__ sq, bf16_t* __restrict__ sk, bf16_t* __restrict__ sv)
{
    const int r = threadIdx.x;
    const int row = blockIdx.x;
    const bf16_t* yrow = y + (size_t)row * 4096;
    const float* fQ = wfQ + row * N_NEU;
    const float* fK = wfK + row * N_NEU;
    const float* fV = wfV + row * N_NEU;
    float aQ = 0.f, aK = 0.f, aV = 0.f;
#pragma unroll
    for (int n = 0; n < N_NEU; n++) {
        float yq = (float)yrow[n * R_DIM + r];
        float yv = (float)yrow[2048 + n * R_DIM + r];
        aQ += fQ[n] * yq;
        aK += fK[n] * yq;
        aV += fV[n] * yv;
    }
    const float* rQ = wrQ + row * N_NEU;
    const float* rK = wrK + row * N_NEU;
    const float* rV = wrV + row * N_NEU;
    const size_t rb = (size_t)row * 2048;
#pragma unroll
    for (int n = 0; n < N_NEU; n++) {
        sq[rb + n * R_DIM + r] = (bf16_t)(rQ[n] * aQ);
        sk[rb + n * R_DIM + r] = (bf16_t)(rK[n] * aK);
        sv[rb + n * R_DIM + r] = (bf16_t)(rV[n] * aV);
    }
}

// know-path ws with fused split-K reduce (R12 form: 2 rows/block, 2048 blocks).
__global__ __launch_bounds__(256)
void ws2_kernel(const bf16_t* __restrict__ P0, const bf16_t* __restrict__ P1,
                const float* __restrict__ wf, const float* __restrict__ wr,
                bf16_t* __restrict__ sout)
{
    const int lr = threadIdx.x >> 7;
    const int r  = threadIdx.x & 127;
    const int row = blockIdx.x * 2 + lr;
    const size_t rb = (size_t)row * (N_NEU * KR_DIM);
    const float* wfp = wf + row * N_NEU;
    const float* wrp = wr + row * N_NEU;
    float acc = 0.f;
#pragma unroll
    for (int n = 0; n < N_NEU; n++) {
        size_t i = rb + n * KR_DIM + r;
        acc += wfp[n] * ((float)P0[i] + (float)P1[i]);
    }
    bf16_t* srow = sout + rb;
#pragma unroll
    for (int n = 0; n < N_NEU; n++) srow[n * KR_DIM + r] = (bf16_t)(wrp[n] * acc);
}

// ---------------------------------------------------------------------------
// gemm256: C[M,N] = A[M,K] @ Bsel[N,K]^T.  256x128 tile, BK=32, 8 waves,
// single-phase counted-vmcnt 3-buffer pipeline (R12-proven), T2 swizzle.
// EPI=0: bf16 C.  EPI=2: bf16 partial per blockIdx.z (split-K=2).
// ---------------------------------------------------------------------------
template<int EPI>
__global__ __launch_bounds__(512, 2)
void gemm256_kernel(const bf16_t* __restrict__ A, const bf16_t* __restrict__ Bt,
                    const bf16_t* __restrict__ Bt2, int splitMy,
                    void* Cout, int M, int N, int K)
{
    __shared__ bf16_t As[3][256][32];
    __shared__ bf16_t Bs[3][128][32];
    const int tid = threadIdx.x;
    const int l = tid & 63, w = tid >> 6;
    const int wr = w >> 1, wc = w & 1;

    const int nbxy = gridDim.x * gridDim.y;
    int bid = blockIdx.y * gridDim.x + blockIdx.x;
    if ((nbxy & 7) == 0) bid = (bid & 7) * (nbxy >> 3) + (bid >> 3);
    const int bx = bid % gridDim.x, by = bid / gridDim.x;

    const int m0 = by * 256, n0 = bx * 128;
    const bf16_t* Bsel = (by < splitMy) ? Bt : Bt2;

    int kbeg = 0, kend = K;
    if constexpr (EPI == 2) { const int half = K >> 1; kbeg = blockIdx.z * half; kend = kbeg + half; }

    const int strow  = w * 16 + (l >> 2);
    const int scelem = ((((l & 3) * 16) ^ ((strow & 6) << 3)) >> 1);
    const bf16_t* Ag0 = A    + (size_t)(m0 + strow) * K + scelem;
    const bf16_t* Ag1 = A    + (size_t)(m0 + strow + 128) * K + scelem;
    const bf16_t* Bg0 = Bsel + (size_t)(n0 + strow) * K + scelem;

    auto stage = [&](int buf, int k0) {
        char* dA = (char*)&As[buf][0][0] + w * 1024;
        char* dB = (char*)&Bs[buf][0][0] + w * 1024;
        gl_lds16(Ag0 + k0, dA);
        gl_lds16(Ag1 + k0, dA + 8192);
        gl_lds16(Bg0 + k0, dB);
    };

    f32x4 acc[4][4];
    const f32x4 zero = {0.f, 0.f, 0.f, 0.f};
#pragma unroll
    for (int i = 0; i < 4; i++)
#pragma unroll
        for (int j = 0; j < 4; j++) acc[i][j] = zero;

    const int fr  = l & 15;
    const int fkb = (l >> 4) * 16;

    stage(0, kbeg);
    stage(1, kbeg + 32);

    const int nK = (kend - kbeg) >> 5;
    for (int it = 0; it < nK; ++it) {
        if (it + 1 < nK) {
            asm volatile("s_waitcnt vmcnt(3)" ::: "memory");
        } else {
            asm volatile("s_waitcnt vmcnt(0)" ::: "memory");
        }
        __builtin_amdgcn_s_barrier();
        __builtin_amdgcn_sched_barrier(0);

        const int cur = it % 3;
        const char* Ab = (const char*)&As[cur][0][0];
        const char* Bb = (const char*)&Bs[cur][0][0];
        bf16x8 af[4], bv[4];
#pragma unroll
        for (int i = 0; i < 4; i++) {
            const int rowA = wr * 64 + i * 16 + fr;
            af[i] = *(const bf16x8*)(Ab + rowA * 64 + (fkb ^ ((rowA & 6) << 3)));
        }
#pragma unroll
        for (int i = 0; i < 4; i++) {
            const int rowB = wc * 64 + i * 16 + fr;
            bv[i] = *(const bf16x8*)(Bb + rowB * 64 + (fkb ^ ((rowB & 6) << 3)));
        }

        if (it + 2 < nK) stage((it + 2) % 3, kbeg + (it + 2) * 32);

        __builtin_amdgcn_s_setprio(1);
#pragma unroll
        for (int mi = 0; mi < 4; mi++)
#pragma unroll
            for (int ni = 0; ni < 4; ni++)
                acc[mi][ni] = __builtin_amdgcn_mfma_f32_16x16x32_bf16(af[mi], bv[ni], acc[mi][ni], 0, 0, 0);
        __builtin_amdgcn_s_setprio(0);
    }

    const int orow = (l >> 4) * 4;
    const int ocol = l & 15;
#pragma unroll
    for (int mi = 0; mi < 4; mi++)
#pragma unroll
        for (int ni = 0; ni < 4; ni++)
#pragma unroll
            for (int j = 0; j < 4; j++) {
                int row = m0 + wr * 64 + mi * 16 + orow + j;
                int col = n0 + wc * 64 + ni * 16 + ocol;
                size_t idx = (size_t)row * N + col;
                if constexpr (EPI == 0) {
                    ((bf16_t*)Cout)[idx] = (bf16_t)acc[mi][ni][j];
                } else {
                    ((bf16_t*)Cout)[(size_t)blockIdx.z * M * N + idx] = (bf16_t)acc[mi][ni][j];
                }
            }
}

// ---------------------------------------------------------------------------
// Legacy 128x128 GEMM, counted-vmcnt 3-buffer (R10 structure).
// EPI=0: bf16 C.  EPI=1: fp32 C = acc + resid.
// ---------------------------------------------------------------------------
template<int EPI>
__global__ __launch_bounds__(256)
void gemm_kernel(const bf16_t* __restrict__ A, const bf16_t* __restrict__ Bt,
                 const bf16_t* __restrict__ Bt2, int splitMy,
                 void* Cout, const float* resid, int M, int N, int K)
{
    __shared__ bf16_t As[3][128][32];
    __shared__ bf16_t Bs[3][128][32];
    const int tid = threadIdx.x;
    const int l = tid & 63, w = tid >> 6;
    const int wr = w >> 1, wc = w & 1;

    const int nbxy = gridDim.x * gridDim.y;
    int bid = blockIdx.y * gridDim.x + blockIdx.x;
    if ((nbxy & 7) == 0) bid = (bid & 7) * (nbxy >> 3) + (bid >> 3);
    const int bx = bid % gridDim.x, by = bid / gridDim.x;

    const int m0 = by * 128, n0 = bx * 128;
    const bf16_t* Bsel = (by < splitMy) ? Bt : Bt2;

    const int kbeg = 0, kend = K;

    const int srow = l >> 2;
    const int scolswz = (((l & 3) * 16) ^ ((srow & 6) << 3)) >> 1;
    const bf16_t* Ag0 = A    + (size_t)(m0 + w * 32 + srow) * K + scolswz;
    const bf16_t* Ag1 = Ag0 + (size_t)16 * K;
    const bf16_t* Bg0 = Bsel + (size_t)(n0 + w * 32 + srow) * K + scolswz;
    const bf16_t* Bg1 = Bg0 + (size_t)16 * K;

    auto stage = [&](int buf, int k0) {
        char* Asb = (char*)&As[buf][0][0] + w * 2048;
        char* Bsb = (char*)&Bs[buf][0][0] + w * 2048;
        gl_lds16(Ag0 + k0, Asb);
        gl_lds16(Ag1 + k0, Asb + 1024);
        gl_lds16(Bg0 + k0, Bsb);
        gl_lds16(Bg1 + k0, Bsb + 1024);
    };

    f32x4 acc[4][4];
    const f32x4 zero = {0.f, 0.f, 0.f, 0.f};
#pragma unroll
    for (int i = 0; i < 4; i++)
#pragma unroll
        for (int j = 0; j < 4; j++) acc[i][j] = zero;

    const int fr = l & 15;
    const int fkb = (l >> 4) * 16;

    stage(0, kbeg);
    stage(1, kbeg + 32);

    const int nK = (kend - kbeg) >> 5;
    for (int it = 0; it < nK; ++it) {
        if (it + 1 < nK) {
            asm volatile("s_waitcnt vmcnt(4)" ::: "memory");
        } else {
            asm volatile("s_waitcnt vmcnt(0)" ::: "memory");
        }
        __builtin_amdgcn_s_barrier();
        __builtin_amdgcn_sched_barrier(0);

        const int cur = it % 3;
        const char* Ab = (const char*)&As[cur][0][0];
        const char* Bb = (const char*)&Bs[cur][0][0];
        bf16x8 af[4], bv[4];
#pragma unroll
        for (int i = 0; i < 4; i++) {
            const int rowA = wr * 64 + i * 16 + fr;
            af[i] = *(const bf16x8*)(Ab + rowA * 64 + (fkb ^ ((rowA & 6) << 3)));
        }
#pragma unroll
        for (int i = 0; i < 4; i++) {
            const int rowB = wc * 64 + i * 16 + fr;
            bv[i] = *(const bf16x8*)(Bb + rowB * 64 + (fkb ^ ((rowB & 6) << 3)));
        }

        if (it + 2 < nK) stage((it + 2) % 3, kbeg + (it + 2) * 32);

        __builtin_amdgcn_s_setprio(1);
#pragma unroll
        for (int mi = 0; mi < 4; mi++)
#pragma unroll
            for (int ni = 0; ni < 4; ni++)
                acc[mi][ni] = __builtin_amdgcn_mfma_f32_16x16x32_bf16(af[mi], bv[ni], acc[mi][ni], 0, 0, 0);
        __builtin_amdgcn_s_setprio(0);
    }

    const int orow = (l >> 4) * 4;
    const int ocol = l & 15;
#pragma unroll
    for (int mi = 0; mi < 4; mi++)
#pragma unroll
        for (int ni = 0; ni < 4; ni++)
#pragma unroll
            for (int j = 0; j < 4; j++) {
                int row = m0 + wr * 64 + mi * 16 + orow + j;
                int col = n0 + wc * 64 + ni * 16 + ocol;
                size_t idx = (size_t)row * N + col;
                if constexpr (EPI == 0) {
                    ((bf16_t*)Cout)[idx] = (bf16_t)acc[mi][ni][j];
                } else {
                    ((float*)Cout)[idx] = acc[mi][ni][j] + resid[idx];
                }
            }
}

// ---------------------------------------------------------------------------
// Causal flash attention, KVBLK=64, single-barrier double-buffered LDS.
// LDS = Ks[2][64][64] + Vs[2][64][64] + Ps[4][16][64] = 40 KB -> 4 blocks/CU.
// All strided-row LDS accesses XOR-swizzled: byte ^= ((row&7)<<4).
// Balanced R5 map: per-CU slot set {t,15-t,16+t,31-t} -> 66 tiles/CU exact.
// Per tile: write buf^1 (regs from last iter) || issue loads t+2 || compute
// buf || ONE barrier.  exp2 softmax, defer-max, MFMA l-sum, diag-only mask.
// ---------------------------------------------------------------------------
__global__ __launch_bounds__(256, 4)
void fa_kernel(const bf16_t* __restrict__ Q, const bf16_t* __restrict__ K,
               const bf16_t* __restrict__ Vt, bf16_t* __restrict__ O)
{
    __shared__ bf16_t Ks[2][64][64];
    __shared__ bf16_t Vs[2][64][64];
    __shared__ bf16_t Ps[4][16][64];

    const int tid = threadIdx.x;
    const int l = tid & 63, w = tid >> 6;

    const int bid  = blockIdx.x;
    const int xcd  = bid & 7;
    const int slot = bid >> 3;          // 0..127
    const int head = slot & 3;
    const int j5   = slot >> 2;         // 0..31
    const int t5   = j5 & 7, u5 = j5 >> 3;
    const int qb   = 8 * u5 + ((u5 & 1) ? (7 - t5) : t5);
    const int bh   = xcd * 4 + head;
    const int b = bh >> 4, h = bh & 15;
    const int q0 = qb * 64;
    const int nt = qb + 1;              // 64-key tiles

    const bf16_t* Qp = Q + (size_t)b * S_LEN * D_DIM + h * DH;
    const bf16_t* Kp = K + (size_t)b * S_LEN * D_DIM + h * DH;
    const bf16_t* Vp = Vt + (size_t)b * D_DIM * S_LEN + (size_t)h * DH * S_LEN;

    const int fr = l & 15, fg = l >> 4, fk = fg * 8;
    const int srow = tid >> 2;          // 0..63
    const int scel = (tid & 3) * 16;    // element base 0,16,32,48
    const int swz  = (srow & 7) << 4;   // staging swizzle (byte)
    const bf16_t* Kst = Kp + (size_t)srow * D_DIM + scel;
    const bf16_t* Vst = Vp + (size_t)srow * S_LEN + scel;

    bf16x8 ones8;
#pragma unroll
    for (int i = 0; i < 8; i++) ones8[i] = (bf16_t)1.f;

    const f32x4 zero = {0.f, 0.f, 0.f, 0.f};
    const float C_LOG2 = 0.125f * 1.44269504f;

    bf16x8 qf[2];
#pragma unroll
    for (int ks = 0; ks < 2; ks++)
        qf[ks] = *(const bf16x8*)(Qp + (size_t)(q0 + w * 16 + fr) * D_DIM + ks * 32 + fk);

    f32x4 o[4];
    f32x4 la = zero;
    float m_r[4];
#pragma unroll
    for (int j = 0; j < 4; j++) { o[j] = zero; m_r[j] = -1e30f; }

    // ---- prologue: load tile0 regs, write buf0, load tile1 regs ----
    uint4 ka = *(const uint4*)(Kst);
    uint4 kb = *(const uint4*)(Kst + 8);
    uint4 va = *(const uint4*)(Vst);
    uint4 vb = *(const uint4*)(Vst + 8);
    {
        char* kd = (char*)&Ks[0][srow][0];
        char* vd = (char*)&Vs[0][srow][0];
        *(uint4*)(kd + ((scel * 2)      ^ swz)) = ka;
        *(uint4*)(kd + ((scel * 2 + 16) ^ swz)) = kb;
        *(uint4*)(vd + ((scel * 2)      ^ swz)) = va;
        *(uint4*)(vd + ((scel * 2 + 16) ^ swz)) = vb;
    }
    if (nt > 1) {
        ka = *(const uint4*)(Kst + (size_t)64 * D_DIM);
        kb = *(const uint4*)(Kst + (size_t)64 * D_DIM + 8);
        va = *(const uint4*)(Vst + 64);
        vb = *(const uint4*)(Vst + 64 + 8);
    }
    __syncthreads();

    for (int t = 0; t < nt; t++) {
        const int cur = t & 1;

        // (1) write buf^1 with tile t+1 regs (loaded during iter t-1 / prologue)
        if (t + 1 < nt) {
            char* kd = (char*)&Ks[cur ^ 1][srow][0];
            char* vd = (char*)&Vs[cur ^ 1][srow][0];
            *(uint4*)(kd + ((scel * 2)      ^ swz)) = ka;
            *(uint4*)(kd + ((scel * 2 + 16) ^ swz)) = kb;
            *(uint4*)(vd + ((scel * 2)      ^ swz)) = va;
            *(uint4*)(vd + ((scel * 2 + 16) ^ swz)) = vb;
        }
        // (2) issue loads for tile t+2
        if (t + 2 < nt) {
            const size_t kn = (size_t)(t + 2) * 64;
            ka = *(const uint4*)(Kst + kn * D_DIM);
            kb = *(const uint4*)(Kst + kn * D_DIM + 8);
            va = *(const uint4*)(Vst + kn);
            vb = *(const uint4*)(Vst + kn + 8);
        }

        // (3) compute tile t from buf cur
        const int k0 = t * 64;
        f32x4 sc[4];
#pragma unroll
        for (int ni = 0; ni < 4; ni++) sc[ni] = zero;
        __builtin_amdgcn_s_setprio(1);
#pragma unroll
        for (int ks = 0; ks < 2; ks++) {
#pragma unroll
            for (int ni = 0; ni < 4; ni++) {
                const int row = ni * 16 + fr;
                bf16x8 kf = *(const bf16x8*)((const char*)&Ks[cur][row][0]
                              + ((ks * 64 + fg * 16) ^ ((fr & 7) << 4)));
                sc[ni] = __builtin_amdgcn_mfma_f32_16x16x32_bf16(qf[ks], kf, sc[ni], 0, 0, 0);
            }
        }
        __builtin_amdgcn_s_setprio(0);

        // scale + causal mask (diag tile only)
        float p[4][4];
        if (t == qb) {
#pragma unroll
            for (int ni = 0; ni < 4; ni++) {
                const int key = k0 + ni * 16 + fr;
#pragma unroll
                for (int j = 0; j < 4; j++) {
                    const int qg = q0 + w * 16 + fg * 4 + j;
                    p[ni][j] = (key <= qg) ? sc[ni][j] * C_LOG2 : -1e30f;
                }
            }
        } else {
#pragma unroll
            for (int ni = 0; ni < 4; ni++)
#pragma unroll
                for (int j = 0; j < 4; j++)
                    p[ni][j] = sc[ni][j] * C_LOG2;
        }

        // online softmax (exp2 domain), defer-max
#pragma unroll
        for (int j = 0; j < 4; j++) {
            float rmax = fmaxf(fmaxf(p[0][j], p[1][j]), fmaxf(p[2][j], p[3][j]));
#pragma unroll
            for (int d = 1; d < 16; d <<= 1) rmax = fmaxf(rmax, __shfl_xor(rmax, d));
            if (rmax > m_r[j] + 8.f) {
                float scale = exp2f(m_r[j] - rmax);
                la[j] *= scale;
#pragma unroll
                for (int nc = 0; nc < 4; nc++) o[nc][j] *= scale;
                m_r[j] = rmax;
            }
#pragma unroll
            for (int ni = 0; ni < 4; ni++)
                p[ni][j] = exp2f(p[ni][j] - m_r[j]);
        }

        // P -> A-layout via per-wave swizzled LDS bounce
#pragma unroll
        for (int ni = 0; ni < 4; ni++)
#pragma unroll
            for (int j = 0; j < 4; j++) {
                const int qrow = fg * 4 + j;
                char* pd = (char*)&Ps[w][qrow][0];
                *(bf16_t*)(pd + (((ni * 16 + fr) * 2) ^ ((qrow & 7) << 4))) = (bf16_t)p[ni][j];
            }

        // PV + l-sum
        __builtin_amdgcn_s_setprio(1);
#pragma unroll
        for (int ks = 0; ks < 2; ks++) {
            bf16x8 pa = *(const bf16x8*)((const char*)&Ps[w][fr][0]
                          + ((ks * 64 + fg * 16) ^ ((fr & 7) << 4)));
            la = __builtin_amdgcn_mfma_f32_16x16x32_bf16(pa, ones8, la, 0, 0, 0);
#pragma unroll
            for (int nc = 0; nc < 4; nc++) {
                const int row = nc * 16 + fr;
                bf16x8 vf = *(const bf16x8*)((const char*)&Vs[cur][row][0]
                              + ((ks * 64 + fg * 16) ^ ((fr & 7) << 4)));
                o[nc] = __builtin_amdgcn_mfma_f32_16x16x32_bf16(pa, vf, o[nc], 0, 0, 0);
            }
        }
        __builtin_amdgcn_s_setprio(0);

        // (4) one barrier per tile
        __syncthreads();
    }

    // ---- epilogue ----
#pragma unroll
    for (int j = 0; j < 4; j++) {
        const float inv = 1.f / la[j];
        const int q = q0 + w * 16 + fg * 4 + j;
        bf16_t* op = O + (size_t)(b * S_LEN + q) * D_DIM + h * DH;
#pragma unroll
        for (int nc = 0; nc < 4; nc++)
            op[nc * 16 + fr] = (bf16_t)(o[nc][j] * inv);
    }
}

// ---------------------------------------------------------------------------
extern "C" void kernel_launch(void* const* d_in, const int* in_sizes, int n_in,
                              void* d_out, int out_size, void* d_ws, size_t ws_size,
                              hipStream_t stream)
{
    const float* x      = (const float*)d_in[0];
    const float* fqk_wQ = (const float*)d_in[1];
    const float* fqk_wK = (const float*)d_in[2];
    const float* fv_w   = (const float*)d_in[3];
    const float* rqk_wQ = (const float*)d_in[4];
    const float* rqk_wK = (const float*)d_in[5];
    const float* rv_w   = (const float*)d_in[6];
    const float* fkn_w  = (const float*)d_in[7];
    const float* rkn_w  = (const float*)d_in[8];
    const float* f_qk   = (const float*)d_in[9];
    const float* f_v    = (const float*)d_in[10];
    const float* r_qk   = (const float*)d_in[11];
    const float* r_v    = (const float*)d_in[12];
    const float* f_know = (const float*)d_in[13];
    const float* r_know = (const float*)d_in[14];
    const float* W_O    = (const float*)d_in[15];
    const float* ln1g   = (const float*)d_in[16];
    const float* ln1b   = (const float*)d_in[17];
    const float* ln2g   = (const float*)d_in[18];
    const float* ln2b   = (const float*)d_in[19];
    float* out_f = (float*)d_out;
    (void)ws_size; (void)in_sizes; (void)n_in; (void)out_size;

    // ---- workspace layout (reused slots) ----
    char* ws = (char*)d_ws;
    const size_t MB = 1024 * 1024;
    bf16_t* rqkT   = (bf16_t*)(ws + 0 * MB);
    bf16_t* rvT    = (bf16_t*)(ws + 4 * MB);
    bf16_t* rknT   = (bf16_t*)(ws + 8 * MB);
    bf16_t* woB    = (bf16_t*)(ws + 10 * MB);
    bf16_t* fknT   = (bf16_t*)(ws + 12 * MB);
    bf16_t* buf_nx = (bf16_t*)(ws + 14 * MB);   // nx -> Vt -> nx2
    bf16_t* buf_y  = (bf16_t*)(ws + 22 * MB);   // y -> QKV
    char*   buf_s  = ws + 54 * MB;
    bf16_t* fqkT   = (bf16_t*)(buf_s);
    bf16_t* fvT    = (bf16_t*)(buf_s + 4 * MB);
    bf16_t* s_q    = (bf16_t*)(buf_s);
    bf16_t* s_k    = (bf16_t*)(buf_s) + (size_t)4096 * 2048;
    bf16_t* s_v    = (bf16_t*)(buf_s) + (size_t)8192 * 2048;
    bf16_t* attn   = (bf16_t*)(buf_s);
    bf16_t* P0     = (bf16_t*)(buf_s + 16 * MB);
    bf16_t* P0k    = (bf16_t*)(buf_s);
    bf16_t* sk2    = (bf16_t*)(buf_s + 32 * MB);
    bf16_t* Qb     = buf_y;
    bf16_t* Kb     = buf_y + (size_t)4096 * 1024;
    bf16_t* Vb     = buf_y + (size_t)8192 * 1024;
    bf16_t* Vt     = buf_nx;

    const dim3 blk256(256), blk512(512), blkT(32, 8);

    // ---- weight conversion ----
    tcast_kernel<<<dim3(R_DIM / 32, D_DIM / 32, N_NEU), blkT, 0, stream>>>(f_qk, fqkT, D_DIM, R_DIM);
    tcast_kernel<<<dim3(R_DIM / 32, D_DIM / 32, N_NEU), blkT, 0, stream>>>(f_v, fvT, D_DIM, R_DIM);
    tcast_kernel<<<dim3(KR_DIM / 32, D_DIM / 32, N_NEU), blkT, 0, stream>>>(f_know, fknT, D_DIM, KR_DIM);
    tcast_kernel<<<dim3(D_DIM / 32, 2048 / 32, 1), blkT, 0, stream>>>(r_qk, rqkT, 2048, D_DIM);
    tcast_kernel<<<dim3(D_DIM / 32, 2048 / 32, 1), blkT, 0, stream>>>(r_v, rvT, 2048, D_DIM);
    tcast_kernel<<<dim3(D_DIM / 32, 1024 / 32, 1), blkT, 0, stream>>>(r_know, rknT, 1024, D_DIM);
    cast_kernel<<<dim3(1024 * 1024 / 4 / 256), blk256, 0, stream>>>(W_O, woB, 1024 * 1024 / 4);

    // ---- LN1 ----
    ln_kernel<<<dim3(ROWS), blk256, 0, stream>>>(x, ln1g, ln1b, buf_nx);

    // ---- fused feature GEMM (512 blocks, 2/CU) ----
    gemm256_kernel<0><<<dim3(32, 16), blk512, 0, stream>>>(buf_nx, fqkT, fqkT, 1 << 30, buf_y, 4096, 4096, 1024);

    // ---- fused weighted sums (4096 blocks) ----
    wsf_kernel<<<dim3(ROWS), blk256, 0, stream>>>(buf_y, fqk_wQ, rqk_wQ, fqk_wK, rqk_wK, fv_w, rv_w, s_q, s_k, s_v);

    // ---- grouped restore GEMM: 128^2 legacy, 768 blocks = 3/CU balanced ----
    gemm_kernel<0><<<dim3(8, 96), blk256, 0, stream>>>((bf16_t*)buf_s, rqkT, rvT, 64, buf_y, nullptr, 12288, 1024, 2048);

    // ---- V -> Vt ----
    tbf_kernel<<<dim3(D_DIM / 32, S_LEN / 32, B_DIM), blkT, 0, stream>>>(Vb, Vt, S_LEN, D_DIM);

    // ---- attention (1024 blocks, 4/CU, dbuf single-barrier) ----
    fa_kernel<<<dim3(1024), blk256, 0, stream>>>(Qb, Kb, Vt, attn);

    // ---- W_O split-K=2: bf16 partials (256 blocks) ----
    gemm256_kernel<2><<<dim3(8, 16, 2), blk512, 0, stream>>>(attn, woB, woB, 1 << 30, P0, 4096, 1024, 1024);

    // ---- LN2 fused ----
    ln2x_kernel<<<dim3(ROWS), blk256, 0, stream>>>(x, P0, P0 + (size_t)4096 * 1024, ln2g, ln2b, out_f, buf_nx);

    // ---- know feature split-K=2: bf16 partials (256 blocks) ----
    gemm256_kernel<2><<<dim3(8, 16, 2), blk512, 0, stream>>>(buf_nx, fknT, fknT, 1 << 30, P0k, 4096, 1024, 1024);

    // ---- know ws (2048 blocks) ----
    ws2_kernel<<<dim3(ROWS / 2), blk256, 0, stream>>>(P0k, P0k + (size_t)4096 * 1024, fkn_w, rkn_w, sk2);

    // ---- out = sk2 @ rknT^T + x2 -> d_out ----
    gemm_kernel<1><<<dim3(8, 32), blk256, 0, stream>>>(sk2, rknT, rknT, 1 << 30, d_out, out_f, 4096, 1024, 1024);
}

// Round 15
// 283.942 us; speedup vs baseline: 1.1103x; 1.1103x over previous
//
#include <hip/hip_runtime.h>
#include <hip/hip_bf16.h>

// ---------------------------------------------------------------------------
// DAWN block on MI355X.  Round 15 = R12 (best verified, 290.7us) + fa T13
// fast-path: per-lane pmax + wave-uniform __any gate replaces the per-tile
// 16-shfl max tree (tree runs only when a row's max actually grows).
// ---------------------------------------------------------------------------

typedef __bf16 bf16_t;
typedef __bf16 bf16x4 __attribute__((ext_vector_type(4)));
typedef __bf16 bf16x8 __attribute__((ext_vector_type(8)));
typedef float f32x4 __attribute__((ext_vector_type(4)));

#define B_DIM 2
#define S_LEN 2048
#define D_DIM 1024
#define H_NUM 16
#define DH 64
#define N_NEU 8
#define R_DIM 256
#define KR_DIM 128
#define ROWS (B_DIM * S_LEN)   // 4096

static __device__ __forceinline__ void gl_lds16(const void* g, void* l)
{
    __builtin_amdgcn_global_load_lds(
        (__attribute__((address_space(1))) void*)(g),
        (__attribute__((address_space(3))) void*)(l), 16, 0, 0);
}

// ---------------------------------------------------------------------------
// Batched transpose-cast: in[z][I][J] f32 -> out[z][J][I] bf16.  block (32,8)
// ---------------------------------------------------------------------------
__global__ __launch_bounds__(256)
void tcast_kernel(const float* __restrict__ in, bf16_t* __restrict__ out, int I, int J)
{
    __shared__ float t[32][33];
    const int bJ = blockIdx.x * 32, bI = blockIdx.y * 32;
    const size_t boff = (size_t)blockIdx.z * I * J;
    const int tx = threadIdx.x, ty = threadIdx.y;
#pragma unroll
    for (int i = 0; i < 4; i++)
        t[ty * 4 + i][tx] = in[boff + (size_t)(bI + ty * 4 + i) * J + bJ + tx];
    __syncthreads();
#pragma unroll
    for (int i = 0; i < 4; i++)
        out[boff + (size_t)(bJ + ty * 4 + i) * I + bI + tx] = (bf16_t)t[tx][ty * 4 + i];
}

// bf16 transpose: in[z][I][J] -> out[z][J][I].  block (32,8)
__global__ __launch_bounds__(256)
void tbf_kernel(const bf16_t* __restrict__ in, bf16_t* __restrict__ out, int I, int J)
{
    __shared__ bf16_t t[32][33];
    const int bJ = blockIdx.x * 32, bI = blockIdx.y * 32;
    const size_t boff = (size_t)blockIdx.z * I * J;
    const int tx = threadIdx.x, ty = threadIdx.y;
#pragma unroll
    for (int i = 0; i < 4; i++)
        t[ty * 4 + i][tx] = in[boff + (size_t)(bI + ty * 4 + i) * J + bJ + tx];
    __syncthreads();
#pragma unroll
    for (int i = 0; i < 4; i++)
        out[boff + (size_t)(bJ + ty * 4 + i) * I + bI + tx] = t[tx][ty * 4 + i];
}

// plain cast fp32 -> bf16 (vectorized by 4)
__global__ __launch_bounds__(256)
void cast_kernel(const float* __restrict__ in, bf16_t* __restrict__ out, int n4)
{
    int i = blockIdx.x * 256 + threadIdx.x;
    if (i < n4) {
        float4 v = ((const float4*)in)[i];
        bf16_t* op = out + (size_t)i * 4;
        op[0] = (bf16_t)v.x; op[1] = (bf16_t)v.y; op[2] = (bf16_t)v.z; op[3] = (bf16_t)v.w;
    }
}

// ---------------------------------------------------------------------------
// LayerNorm over D=1024, one row per block. fp32 in, bf16 out.
// ---------------------------------------------------------------------------
__global__ __launch_bounds__(256)
void ln_kernel(const float* __restrict__ x, const float* __restrict__ g,
               const float* __restrict__ beta, bf16_t* __restrict__ out)
{
    __shared__ float red[4];
    const int row = blockIdx.x;
    const int tid = threadIdx.x;
    float4 v = *(const float4*)&x[(size_t)row * D_DIM + tid * 4];

    float s = v.x + v.y + v.z + v.w;
#pragma unroll
    for (int o = 32; o; o >>= 1) s += __shfl_down(s, o);
    if ((tid & 63) == 0) red[tid >> 6] = s;
    __syncthreads();
    float mean = (red[0] + red[1] + red[2] + red[3]) * (1.f / D_DIM);
    __syncthreads();

    float dx = v.x - mean, dy = v.y - mean, dz = v.z - mean, dw = v.w - mean;
    float q = dx * dx + dy * dy + dz * dz + dw * dw;
#pragma unroll
    for (int o = 32; o; o >>= 1) q += __shfl_down(q, o);
    if ((tid & 63) == 0) red[tid >> 6] = q;
    __syncthreads();
    float var = (red[0] + red[1] + red[2] + red[3]) * (1.f / D_DIM);
    float rstd = rsqrtf(var + 1e-5f);

    float4 gv = *(const float4*)&g[tid * 4];
    float4 bv = *(const float4*)&beta[tid * 4];
    bf16_t* op = out + (size_t)row * D_DIM + tid * 4;
    op[0] = (bf16_t)(dx * rstd * gv.x + bv.x);
    op[1] = (bf16_t)(dy * rstd * gv.y + bv.y);
    op[2] = (bf16_t)(dz * rstd * gv.z + bv.z);
    op[3] = (bf16_t)(dw * rstd * gv.w + bv.w);
}

// ---------------------------------------------------------------------------
// LN2 with fused split-K reduce (bf16 partials) + residual.
// ---------------------------------------------------------------------------
__global__ __launch_bounds__(256)
void ln2x_kernel(const float* __restrict__ x, const bf16_t* __restrict__ P0,
                 const bf16_t* __restrict__ P1, const float* __restrict__ g,
                 const float* __restrict__ beta, float* __restrict__ outf,
                 bf16_t* __restrict__ outn)
{
    __shared__ float red[4];
    const int row = blockIdx.x;
    const int tid = threadIdx.x;
    const size_t base = (size_t)row * D_DIM + tid * 4;
    float4 v  = *(const float4*)&x[base];
    bf16x4 p0 = *(const bf16x4*)&P0[base];
    bf16x4 p1 = *(const bf16x4*)&P1[base];
    v.x += (float)p0[0] + (float)p1[0];
    v.y += (float)p0[1] + (float)p1[1];
    v.z += (float)p0[2] + (float)p1[2];
    v.w += (float)p0[3] + (float)p1[3];
    *(float4*)&outf[base] = v;

    float s = v.x + v.y + v.z + v.w;
#pragma unroll
    for (int o = 32; o; o >>= 1) s += __shfl_down(s, o);
    if ((tid & 63) == 0) red[tid >> 6] = s;
    __syncthreads();
    float mean = (red[0] + red[1] + red[2] + red[3]) * (1.f / D_DIM);
    __syncthreads();

    float dx = v.x - mean, dy = v.y - mean, dz = v.z - mean, dw = v.w - mean;
    float q = dx * dx + dy * dy + dz * dz + dw * dw;
#pragma unroll
    for (int o = 32; o; o >>= 1) q += __shfl_down(q, o);
    if ((tid & 63) == 0) red[tid >> 6] = q;
    __syncthreads();
    float var = (red[0] + red[1] + red[2] + red[3]) * (1.f / D_DIM);
    float rstd = rsqrtf(var + 1e-5f);

    float4 gv = *(const float4*)&g[tid * 4];
    float4 bv = *(const float4*)&beta[tid * 4];
    bf16_t* op = outn + base;
    op[0] = (bf16_t)(dx * rstd * gv.x + bv.x);
    op[1] = (bf16_t)(dy * rstd * gv.y + bv.y);
    op[2] = (bf16_t)(dz * rstd * gv.z + bv.z);
    op[3] = (bf16_t)(dw * rstd * gv.w + bv.w);
}

// ---------------------------------------------------------------------------
// Fused weighted-sum for Q/K/V (1 row/block, 4096 blocks).
// ---------------------------------------------------------------------------
__global__ __launch_bounds__(256)
void wsf_kernel(const bf16_t* __restrict__ y,
                const float* __restrict__ wfQ, const float* __restrict__ wrQ,
                const float* __restrict__ wfK, const float* __restrict__ wrK,
                const float* __restrict__ wfV, const float* __restrict__ wrV,
                bf16_t* __restrict__ sq, bf16_t* __restrict__ sk, bf16_t* __restrict__ sv)
{
    const int r = threadIdx.x;
    const int row = blockIdx.x;
    const bf16_t* yrow = y + (size_t)row * 4096;
    const float* fQ = wfQ + row * N_NEU;
    const float* fK = wfK + row * N_NEU;
    const float* fV = wfV + row * N_NEU;
    float aQ = 0.f, aK = 0.f, aV = 0.f;
#pragma unroll
    for (int n = 0; n < N_NEU; n++) {
        float yq = (float)yrow[n * R_DIM + r];
        float yv = (float)yrow[2048 + n * R_DIM + r];
        aQ += fQ[n] * yq;
        aK += fK[n] * yq;
        aV += fV[n] * yv;
    }
    const float* rQ = wrQ + row * N_NEU;
    const float* rK = wrK + row * N_NEU;
    const float* rV = wrV + row * N_NEU;
    const size_t rb = (size_t)row * 2048;
#pragma unroll
    for (int n = 0; n < N_NEU; n++) {
        sq[rb + n * R_DIM + r] = (bf16_t)(rQ[n] * aQ);
        sk[rb + n * R_DIM + r] = (bf16_t)(rK[n] * aK);
        sv[rb + n * R_DIM + r] = (bf16_t)(rV[n] * aV);
    }
}

// know-path ws with fused split-K reduce (2 rows/block, 2048 blocks).
__global__ __launch_bounds__(256)
void ws2_kernel(const bf16_t* __restrict__ P0, const bf16_t* __restrict__ P1,
                const float* __restrict__ wf, const float* __restrict__ wr,
                bf16_t* __restrict__ sout)
{
    const int lr = threadIdx.x >> 7;
    const int r  = threadIdx.x & 127;
    const int row = blockIdx.x * 2 + lr;
    const size_t rb = (size_t)row * (N_NEU * KR_DIM);
    const float* wfp = wf + row * N_NEU;
    const float* wrp = wr + row * N_NEU;
    float acc = 0.f;
#pragma unroll
    for (int n = 0; n < N_NEU; n++) {
        size_t i = rb + n * KR_DIM + r;
        acc += wfp[n] * ((float)P0[i] + (float)P1[i]);
    }
    bf16_t* srow = sout + rb;
#pragma unroll
    for (int n = 0; n < N_NEU; n++) srow[n * KR_DIM + r] = (bf16_t)(wrp[n] * acc);
}

// ---------------------------------------------------------------------------
// gemm256: C[M,N] = A[M,K] @ Bsel[N,K]^T.  256x128 tile, BK=32, 8 waves,
// single-phase counted-vmcnt 3-buffer pipeline, T2 swizzle (R12-proven).
// EPI=0: bf16 C.  EPI=2: bf16 partial per blockIdx.z (split-K=2).
// ---------------------------------------------------------------------------
template<int EPI>
__global__ __launch_bounds__(512, 2)
void gemm256_kernel(const bf16_t* __restrict__ A, const bf16_t* __restrict__ Bt,
                    const bf16_t* __restrict__ Bt2, int splitMy,
                    void* Cout, int M, int N, int K)
{
    __shared__ bf16_t As[3][256][32];
    __shared__ bf16_t Bs[3][128][32];
    const int tid = threadIdx.x;
    const int l = tid & 63, w = tid >> 6;
    const int wr = w >> 1, wc = w & 1;

    const int nbxy = gridDim.x * gridDim.y;
    int bid = blockIdx.y * gridDim.x + blockIdx.x;
    if ((nbxy & 7) == 0) bid = (bid & 7) * (nbxy >> 3) + (bid >> 3);
    const int bx = bid % gridDim.x, by = bid / gridDim.x;

    const int m0 = by * 256, n0 = bx * 128;
    const bf16_t* Bsel = (by < splitMy) ? Bt : Bt2;

    int kbeg = 0, kend = K;
    if constexpr (EPI == 2) { const int half = K >> 1; kbeg = blockIdx.z * half; kend = kbeg + half; }

    const int strow  = w * 16 + (l >> 2);
    const int scelem = ((((l & 3) * 16) ^ ((strow & 6) << 3)) >> 1);
    const bf16_t* Ag0 = A    + (size_t)(m0 + strow) * K + scelem;
    const bf16_t* Ag1 = A    + (size_t)(m0 + strow + 128) * K + scelem;
    const bf16_t* Bg0 = Bsel + (size_t)(n0 + strow) * K + scelem;

    auto stage = [&](int buf, int k0) {
        char* dA = (char*)&As[buf][0][0] + w * 1024;
        char* dB = (char*)&Bs[buf][0][0] + w * 1024;
        gl_lds16(Ag0 + k0, dA);
        gl_lds16(Ag1 + k0, dA + 8192);
        gl_lds16(Bg0 + k0, dB);
    };

    f32x4 acc[4][4];
    const f32x4 zero = {0.f, 0.f, 0.f, 0.f};
#pragma unroll
    for (int i = 0; i < 4; i++)
#pragma unroll
        for (int j = 0; j < 4; j++) acc[i][j] = zero;

    const int fr  = l & 15;
    const int fkb = (l >> 4) * 16;

    stage(0, kbeg);
    stage(1, kbeg + 32);

    const int nK = (kend - kbeg) >> 5;
    for (int it = 0; it < nK; ++it) {
        if (it + 1 < nK) {
            asm volatile("s_waitcnt vmcnt(3)" ::: "memory");
        } else {
            asm volatile("s_waitcnt vmcnt(0)" ::: "memory");
        }
        __builtin_amdgcn_s_barrier();
        __builtin_amdgcn_sched_barrier(0);

        const int cur = it % 3;
        const char* Ab = (const char*)&As[cur][0][0];
        const char* Bb = (const char*)&Bs[cur][0][0];
        bf16x8 af[4], bv[4];
#pragma unroll
        for (int i = 0; i < 4; i++) {
            const int rowA = wr * 64 + i * 16 + fr;
            af[i] = *(const bf16x8*)(Ab + rowA * 64 + (fkb ^ ((rowA & 6) << 3)));
        }
#pragma unroll
        for (int i = 0; i < 4; i++) {
            const int rowB = wc * 64 + i * 16 + fr;
            bv[i] = *(const bf16x8*)(Bb + rowB * 64 + (fkb ^ ((rowB & 6) << 3)));
        }

        if (it + 2 < nK) stage((it + 2) % 3, kbeg + (it + 2) * 32);

        __builtin_amdgcn_s_setprio(1);
#pragma unroll
        for (int mi = 0; mi < 4; mi++)
#pragma unroll
            for (int ni = 0; ni < 4; ni++)
                acc[mi][ni] = __builtin_amdgcn_mfma_f32_16x16x32_bf16(af[mi], bv[ni], acc[mi][ni], 0, 0, 0);
        __builtin_amdgcn_s_setprio(0);
    }

    const int orow = (l >> 4) * 4;
    const int ocol = l & 15;
#pragma unroll
    for (int mi = 0; mi < 4; mi++)
#pragma unroll
        for (int ni = 0; ni < 4; ni++)
#pragma unroll
            for (int j = 0; j < 4; j++) {
                int row = m0 + wr * 64 + mi * 16 + orow + j;
                int col = n0 + wc * 64 + ni * 16 + ocol;
                size_t idx = (size_t)row * N + col;
                if constexpr (EPI == 0) {
                    ((bf16_t*)Cout)[idx] = (bf16_t)acc[mi][ni][j];
                } else {
                    ((bf16_t*)Cout)[(size_t)blockIdx.z * M * N + idx] = (bf16_t)acc[mi][ni][j];
                }
            }
}

// ---------------------------------------------------------------------------
// Legacy 128x128 GEMM (EPI=1 only: fp32 C = acc + resid).
// ---------------------------------------------------------------------------
template<int EPI>
__global__ __launch_bounds__(256)
void gemm_kernel(const bf16_t* __restrict__ A, const bf16_t* __restrict__ Bt,
                 const bf16_t* __restrict__ Bt2, int splitMy,
                 void* Cout, const float* resid, int M, int N, int K)
{
    __shared__ bf16_t As[3][128][32];
    __shared__ bf16_t Bs[3][128][32];
    const int tid = threadIdx.x;
    const int l = tid & 63, w = tid >> 6;
    const int wr = w >> 1, wc = w & 1;

    const int nbxy = gridDim.x * gridDim.y;
    int bid = blockIdx.y * gridDim.x + blockIdx.x;
    if ((nbxy & 7) == 0) bid = (bid & 7) * (nbxy >> 3) + (bid >> 3);
    const int bx = bid % gridDim.x, by = bid / gridDim.x;

    const int m0 = by * 128, n0 = bx * 128;
    const bf16_t* Bsel = (by < splitMy) ? Bt : Bt2;

    const int kbeg = 0, kend = K;

    const int srow = l >> 2;
    const int scolswz = (((l & 3) * 16) ^ ((srow & 6) << 3)) >> 1;
    const bf16_t* Ag0 = A    + (size_t)(m0 + w * 32 + srow) * K + scolswz;
    const bf16_t* Ag1 = Ag0 + (size_t)16 * K;
    const bf16_t* Bg0 = Bsel + (size_t)(n0 + w * 32 + srow) * K + scolswz;
    const bf16_t* Bg1 = Bg0 + (size_t)16 * K;

    auto stage = [&](int buf, int k0) {
        char* Asb = (char*)&As[buf][0][0] + w * 2048;
        char* Bsb = (char*)&Bs[buf][0][0] + w * 2048;
        gl_lds16(Ag0 + k0, Asb);
        gl_lds16(Ag1 + k0, Asb + 1024);
        gl_lds16(Bg0 + k0, Bsb);
        gl_lds16(Bg1 + k0, Bsb + 1024);
    };

    f32x4 acc[4][4];
    const f32x4 zero = {0.f, 0.f, 0.f, 0.f};
#pragma unroll
    for (int i = 0; i < 4; i++)
#pragma unroll
        for (int j = 0; j < 4; j++) acc[i][j] = zero;

    const int fr = l & 15;
    const int fkb = (l >> 4) * 16;

    stage(0, kbeg);
    stage(1, kbeg + 32);

    const int nK = (kend - kbeg) >> 5;
    for (int it = 0; it < nK; ++it) {
        if (it + 1 < nK) {
            asm volatile("s_waitcnt vmcnt(4)" ::: "memory");
        } else {
            asm volatile("s_waitcnt vmcnt(0)" ::: "memory");
        }
        __builtin_amdgcn_s_barrier();
        __builtin_amdgcn_sched_barrier(0);

        const int cur = it % 3;
        const char* Ab = (const char*)&As[cur][0][0];
        const char* Bb = (const char*)&Bs[cur][0][0];
        bf16x8 af[4], bv[4];
#pragma unroll
        for (int i = 0; i < 4; i++) {
            const int rowA = wr * 64 + i * 16 + fr;
            af[i] = *(const bf16x8*)(Ab + rowA * 64 + (fkb ^ ((rowA & 6) << 3)));
        }
#pragma unroll
        for (int i = 0; i < 4; i++) {
            const int rowB = wc * 64 + i * 16 + fr;
            bv[i] = *(const bf16x8*)(Bb + rowB * 64 + (fkb ^ ((rowB & 6) << 3)));
        }

        if (it + 2 < nK) stage((it + 2) % 3, kbeg + (it + 2) * 32);

        __builtin_amdgcn_s_setprio(1);
#pragma unroll
        for (int mi = 0; mi < 4; mi++)
#pragma unroll
            for (int ni = 0; ni < 4; ni++)
                acc[mi][ni] = __builtin_amdgcn_mfma_f32_16x16x32_bf16(af[mi], bv[ni], acc[mi][ni], 0, 0, 0);
        __builtin_amdgcn_s_setprio(0);
    }

    const int orow = (l >> 4) * 4;
    const int ocol = l & 15;
#pragma unroll
    for (int mi = 0; mi < 4; mi++)
#pragma unroll
        for (int ni = 0; ni < 4; ni++)
#pragma unroll
            for (int j = 0; j < 4; j++) {
                int row = m0 + wr * 64 + mi * 16 + orow + j;
                int col = n0 + wc * 64 + ni * 16 + ocol;
                size_t idx = (size_t)row * N + col;
                ((float*)Cout)[idx] = acc[mi][ni][j] + resid[idx];
            }
}

// ---------------------------------------------------------------------------
// Causal flash attention, KVBLK=128 (two fused 64-key sub-tiles), two-pass
// balanced blocks (R12).  T13 fast-path: per-lane pmax + wave __any gate;
// the 16-shfl max tree runs only when a row's max grows (rare after tile 0).
// ---------------------------------------------------------------------------
__global__ __launch_bounds__(256)
void fa_kernel(const bf16_t* __restrict__ Q, const bf16_t* __restrict__ K,
               const bf16_t* __restrict__ Vt, bf16_t* __restrict__ O)
{
    __shared__ bf16_t Ks[128][72];
    __shared__ bf16_t Vs[64][136];
    __shared__ bf16_t Ps[4][16][136];

    const int tid = threadIdx.x;
    const int l = tid & 63, w = tid >> 6;

    const int bid  = blockIdx.x;
    const int xcd  = bid & 7;
    const int slot = bid >> 3;          // 0..63
    const int head = slot & 3;
    const int jq   = slot >> 2;         // 0..15
    const int bh   = xcd * 4 + head;
    const int b = bh >> 4, h = bh & 15;

    const bf16_t* Qp = Q + (size_t)b * S_LEN * D_DIM + h * DH;
    const bf16_t* Kp = K + (size_t)b * S_LEN * D_DIM + h * DH;
    const bf16_t* Vp = Vt + (size_t)b * D_DIM * S_LEN + (size_t)h * DH * S_LEN;

    const int fr = l & 15, fg = l >> 4, fk = fg * 8;
    const int srow = tid >> 2;          // 0..63
    const int scol = (tid & 3) * 16;    // 0,16,32,48
    const bf16_t* Kst = Kp + (size_t)srow * D_DIM + scol;
    const bf16_t* Vst = Vp + (size_t)srow * S_LEN + scol;

    bf16x8 ones8;
#pragma unroll
    for (int i = 0; i < 8; i++) ones8[i] = (bf16_t)1.f;

    const f32x4 zero = {0.f, 0.f, 0.f, 0.f};
    const float C_LOG2 = 0.125f * 1.44269504f;   // 1/sqrt(DH) * log2(e)

    for (int pass = 0; pass < 2; ++pass) {
        const int qb = pass ? jq : (31 - jq);    // long pass first
        const int q0 = qb * 64;
        const int nt = (qb >> 1) + 1;            // 128-key tiles

        bf16x8 qf[2];
#pragma unroll
        for (int ks = 0; ks < 2; ks++)
            qf[ks] = *(const bf16x8*)(Qp + (size_t)(q0 + w * 16 + fr) * D_DIM + ks * 32 + fk);

        f32x4 o[4];
        f32x4 la = zero;
        float m_r[4];
#pragma unroll
        for (int j = 0; j < 4; j++) { o[j] = zero; m_r[j] = -1e30f; }

        // prologue: issue loads for tile 0
        uint4 kva = *(const uint4*)(Kst);
        uint4 kvb = *(const uint4*)(Kst + 8);
        uint4 kvc = *(const uint4*)(Kst + (size_t)64 * D_DIM);
        uint4 kvd = *(const uint4*)(Kst + (size_t)64 * D_DIM + 8);
        uint4 vva = *(const uint4*)(Vst);
        uint4 vvb = *(const uint4*)(Vst + 8);
        uint4 vvc = *(const uint4*)(Vst + 64);
        uint4 vvd = *(const uint4*)(Vst + 72);

        for (int t = 0; t < nt; t++) {
            const int k0 = t * 128;
            __syncthreads();              // previous tile's reads complete
            *(uint4*)&Ks[srow][scol]          = kva;
            *(uint4*)&Ks[srow][scol + 8]      = kvb;
            *(uint4*)&Ks[64 + srow][scol]     = kvc;
            *(uint4*)&Ks[64 + srow][scol + 8] = kvd;
            *(uint4*)&Vs[srow][scol]          = vva;
            *(uint4*)&Vs[srow][scol + 8]      = vvb;
            *(uint4*)&Vs[srow][64 + scol]     = vvc;
            *(uint4*)&Vs[srow][64 + scol + 8] = vvd;
            __syncthreads();

            if (t + 1 < nt) {             // T14: issue next tile's loads now
                const int kn = k0 + 128;
                kva = *(const uint4*)(Kst + (size_t)kn * D_DIM);
                kvb = *(const uint4*)(Kst + (size_t)kn * D_DIM + 8);
                kvc = *(const uint4*)(Kst + (size_t)(kn + 64) * D_DIM);
                kvd = *(const uint4*)(Kst + (size_t)(kn + 64) * D_DIM + 8);
                vva = *(const uint4*)(Vst + kn);
                vvb = *(const uint4*)(Vst + kn + 8);
                vvc = *(const uint4*)(Vst + kn + 64);
                vvd = *(const uint4*)(Vst + kn + 72);
            }

            // ---- QK^T: 16 q-rows x 128 keys (2 independent sub-tiles) ----
            f32x4 sc[2][4];
#pragma unroll
            for (int s2 = 0; s2 < 2; s2++)
#pragma unroll
                for (int ni = 0; ni < 4; ni++) sc[s2][ni] = zero;
            __builtin_amdgcn_s_setprio(1);
#pragma unroll
            for (int ks = 0; ks < 2; ks++) {
#pragma unroll
                for (int s2 = 0; s2 < 2; s2++)
#pragma unroll
                    for (int ni = 0; ni < 4; ni++) {
                        bf16x8 kf = *(const bf16x8*)&Ks[s2 * 64 + ni * 16 + fr][ks * 32 + fk];
                        sc[s2][ni] = __builtin_amdgcn_mfma_f32_16x16x32_bf16(qf[ks], kf, sc[s2][ni], 0, 0, 0);
                    }
            }
            __builtin_amdgcn_s_setprio(0);

            // ---- scale to log2 domain (+ causal mask only on last tile) ----
            float p[2][4][4];
            if (t == nt - 1) {
#pragma unroll
                for (int s2 = 0; s2 < 2; s2++)
#pragma unroll
                    for (int ni = 0; ni < 4; ni++) {
                        const int key = k0 + s2 * 64 + ni * 16 + fr;
#pragma unroll
                        for (int j = 0; j < 4; j++) {
                            const int qg = q0 + w * 16 + fg * 4 + j;
                            p[s2][ni][j] = (key <= qg) ? sc[s2][ni][j] * C_LOG2 : -1e30f;
                        }
                    }
            } else {
#pragma unroll
                for (int s2 = 0; s2 < 2; s2++)
#pragma unroll
                    for (int ni = 0; ni < 4; ni++)
#pragma unroll
                        for (int j = 0; j < 4; j++)
                            p[s2][ni][j] = sc[s2][ni][j] * C_LOG2;
            }

            // ---- online softmax, T13 fast-path ----
            float pmax[4];
#pragma unroll
            for (int j = 0; j < 4; j++) {
                float m8 = p[0][0][j];
#pragma unroll
                for (int s2 = 0; s2 < 2; s2++)
#pragma unroll
                    for (int ni = 0; ni < 4; ni++) m8 = fmaxf(m8, p[s2][ni][j]);
                pmax[j] = m8;
            }
            bool need = (pmax[0] > m_r[0] + 8.f) || (pmax[1] > m_r[1] + 8.f) ||
                        (pmax[2] > m_r[2] + 8.f) || (pmax[3] > m_r[3] + 8.f);
            if (__any(need)) {            // wave-uniform slow path (tile 0 + rare)
#pragma unroll
                for (int j = 0; j < 4; j++) {
                    float rmax = pmax[j];
#pragma unroll
                    for (int d = 1; d < 16; d <<= 1) rmax = fmaxf(rmax, __shfl_xor(rmax, d));
                    if (rmax > m_r[j] + 8.f) {
                        float scale = exp2f(m_r[j] - rmax);
                        la[j] *= scale;
#pragma unroll
                        for (int nc = 0; nc < 4; nc++) o[nc][j] *= scale;
                        m_r[j] = rmax;
                    }
                }
            }
#pragma unroll
            for (int j = 0; j < 4; j++)
#pragma unroll
                for (int s2 = 0; s2 < 2; s2++)
#pragma unroll
                    for (int ni = 0; ni < 4; ni++)
                        p[s2][ni][j] = exp2f(p[s2][ni][j] - m_r[j]);   // <= 2^8

            // ---- P -> A-layout via per-wave LDS bounce (128 cols) ----
#pragma unroll
            for (int s2 = 0; s2 < 2; s2++)
#pragma unroll
                for (int ni = 0; ni < 4; ni++)
#pragma unroll
                    for (int j = 0; j < 4; j++)
                        Ps[w][fg * 4 + j][s2 * 64 + ni * 16 + fr] = (bf16_t)p[s2][ni][j];

            // ---- PV + l-sum over 128 keys (4 ks steps) ----
            __builtin_amdgcn_s_setprio(1);
#pragma unroll
            for (int ks = 0; ks < 4; ks++) {
                bf16x8 pa = *(const bf16x8*)&Ps[w][fr][ks * 32 + fk];
                la = __builtin_amdgcn_mfma_f32_16x16x32_bf16(pa, ones8, la, 0, 0, 0);
#pragma unroll
                for (int nc = 0; nc < 4; nc++) {
                    bf16x8 vf = *(const bf16x8*)&Vs[nc * 16 + fr][ks * 32 + fk];
                    o[nc] = __builtin_amdgcn_mfma_f32_16x16x32_bf16(pa, vf, o[nc], 0, 0, 0);
                }
            }
            __builtin_amdgcn_s_setprio(0);
        }

        // ---- epilogue for this q-tile ----
#pragma unroll
        for (int j = 0; j < 4; j++) {
            const float inv = 1.f / la[j];
            const int q = q0 + w * 16 + fg * 4 + j;
            bf16_t* op = O + (size_t)(b * S_LEN + q) * D_DIM + h * DH;
#pragma unroll
            for (int nc = 0; nc < 4; nc++)
                op[nc * 16 + fr] = (bf16_t)(o[nc][j] * inv);
        }
    }
}

// ---------------------------------------------------------------------------
extern "C" void kernel_launch(void* const* d_in, const int* in_sizes, int n_in,
                              void* d_out, int out_size, void* d_ws, size_t ws_size,
                              hipStream_t stream)
{
    const float* x      = (const float*)d_in[0];
    const float* fqk_wQ = (const float*)d_in[1];
    const float* fqk_wK = (const float*)d_in[2];
    const float* fv_w   = (const float*)d_in[3];
    const float* rqk_wQ = (const float*)d_in[4];
    const float* rqk_wK = (const float*)d_in[5];
    const float* rv_w   = (const float*)d_in[6];
    const float* fkn_w  = (const float*)d_in[7];
    const float* rkn_w  = (const float*)d_in[8];
    const float* f_qk   = (const float*)d_in[9];
    const float* f_v    = (const float*)d_in[10];
    const float* r_qk   = (const float*)d_in[11];
    const float* r_v    = (const float*)d_in[12];
    const float* f_know = (const float*)d_in[13];
    const float* r_know = (const float*)d_in[14];
    const float* W_O    = (const float*)d_in[15];
    const float* ln1g   = (const float*)d_in[16];
    const float* ln1b   = (const float*)d_in[17];
    const float* ln2g   = (const float*)d_in[18];
    const float* ln2b   = (const float*)d_in[19];
    float* out_f = (float*)d_out;
    (void)ws_size; (void)in_sizes; (void)n_in; (void)out_size;

    // ---- workspace layout (reused slots) ----
    char* ws = (char*)d_ws;
    const size_t MB = 1024 * 1024;
    bf16_t* rqkT   = (bf16_t*)(ws + 0 * MB);
    bf16_t* rvT    = (bf16_t*)(ws + 4 * MB);
    bf16_t* rknT   = (bf16_t*)(ws + 8 * MB);
    bf16_t* woB    = (bf16_t*)(ws + 10 * MB);
    bf16_t* fknT   = (bf16_t*)(ws + 12 * MB);
    bf16_t* buf_nx = (bf16_t*)(ws + 14 * MB);   // nx -> Vt -> nx2
    bf16_t* buf_y  = (bf16_t*)(ws + 22 * MB);   // y -> QKV
    char*   buf_s  = ws + 54 * MB;
    bf16_t* fqkT   = (bf16_t*)(buf_s);
    bf16_t* fvT    = (bf16_t*)(buf_s + 4 * MB);
    bf16_t* s_q    = (bf16_t*)(buf_s);
    bf16_t* s_k    = (bf16_t*)(buf_s) + (size_t)4096 * 2048;
    bf16_t* s_v    = (bf16_t*)(buf_s) + (size_t)8192 * 2048;
    bf16_t* attn   = (bf16_t*)(buf_s);
    bf16_t* P0     = (bf16_t*)(buf_s + 16 * MB);
    bf16_t* P0k    = (bf16_t*)(buf_s);
    bf16_t* sk2    = (bf16_t*)(buf_s + 32 * MB);
    bf16_t* Qb     = buf_y;
    bf16_t* Kb     = buf_y + (size_t)4096 * 1024;
    bf16_t* Vb     = buf_y + (size_t)8192 * 1024;
    bf16_t* Vt     = buf_nx;

    const dim3 blk256(256), blk512(512), blkT(32, 8);

    // ---- weight conversion ----
    tcast_kernel<<<dim3(R_DIM / 32, D_DIM / 32, N_NEU), blkT, 0, stream>>>(f_qk, fqkT, D_DIM, R_DIM);
    tcast_kernel<<<dim3(R_DIM / 32, D_DIM / 32, N_NEU), blkT, 0, stream>>>(f_v, fvT, D_DIM, R_DIM);
    tcast_kernel<<<dim3(KR_DIM / 32, D_DIM / 32, N_NEU), blkT, 0, stream>>>(f_know, fknT, D_DIM, KR_DIM);
    tcast_kernel<<<dim3(D_DIM / 32, 2048 / 32, 1), blkT, 0, stream>>>(r_qk, rqkT, 2048, D_DIM);
    tcast_kernel<<<dim3(D_DIM / 32, 2048 / 32, 1), blkT, 0, stream>>>(r_v, rvT, 2048, D_DIM);
    tcast_kernel<<<dim3(D_DIM / 32, 1024 / 32, 1), blkT, 0, stream>>>(r_know, rknT, 1024, D_DIM);
    cast_kernel<<<dim3(1024 * 1024 / 4 / 256), blk256, 0, stream>>>(W_O, woB, 1024 * 1024 / 4);

    // ---- LN1 ----
    ln_kernel<<<dim3(ROWS), blk256, 0, stream>>>(x, ln1g, ln1b, buf_nx);

    // ---- fused feature GEMM (512 blocks) ----
    gemm256_kernel<0><<<dim3(32, 16), blk512, 0, stream>>>(buf_nx, fqkT, fqkT, 1 << 30, buf_y, 4096, 4096, 1024);

    // ---- fused weighted sums (4096 blocks) ----
    wsf_kernel<<<dim3(ROWS), blk256, 0, stream>>>(buf_y, fqk_wQ, rqk_wQ, fqk_wK, rqk_wK, fv_w, rv_w, s_q, s_k, s_v);

    // ---- grouped restore GEMM: QKV[12288][1024] (384 blocks, B-select) ----
    gemm256_kernel<0><<<dim3(8, 48), blk512, 0, stream>>>((bf16_t*)buf_s, rqkT, rvT, 32, buf_y, 12288, 1024, 2048);

    // ---- V -> Vt ----
    tbf_kernel<<<dim3(D_DIM / 32, S_LEN / 32, B_DIM), blkT, 0, stream>>>(Vb, Vt, S_LEN, D_DIM);

    // ---- attention (512 balanced two-pass blocks, KVBLK=128) ----
    fa_kernel<<<dim3(512), blk256, 0, stream>>>(Qb, Kb, Vt, attn);

    // ---- W_O split-K=2: bf16 partials (256 blocks) ----
    gemm256_kernel<2><<<dim3(8, 16, 2), blk512, 0, stream>>>(attn, woB, woB, 1 << 30, P0, 4096, 1024, 1024);

    // ---- LN2 fused ----
    ln2x_kernel<<<dim3(ROWS), blk256, 0, stream>>>(x, P0, P0 + (size_t)4096 * 1024, ln2g, ln2b, out_f, buf_nx);

    // ---- know feature split-K=2: bf16 partials (256 blocks) ----
    gemm256_kernel<2><<<dim3(8, 16, 2), blk512, 0, stream>>>(buf_nx, fknT, fknT, 1 << 30, P0k, 4096, 1024, 1024);

    // ---- know ws (2048 blocks) ----
    ws2_kernel<<<dim3(ROWS / 2), blk256, 0, stream>>>(P0k, P0k + (size_t)4096 * 1024, fkn_w, rkn_w, sk2);

    // ---- out = sk2 @ rknT^T + x2 -> d_out ----
    gemm_kernel<1><<<dim3(8, 32), blk256, 0, stream>>>(sk2, rknT, rknT, 1 << 30, d_out, out_f, 4096, 1024, 1024);
}

// Round 16
// 277.795 us; speedup vs baseline: 1.1348x; 1.0221x over previous
//
#include <hip/hip_runtime.h>
#include <hip/hip_bf16.h>

// ---------------------------------------------------------------------------
// DAWN block on MI355X.  Round 16 = R15 + fa restructure:
//  - 512 blocks x 8 waves, Q-tile 128 (16 rows/wave), KVBLK=64
//  - K/V staged via global_load_lds with T2 pre-swizzled source (GEMM-proven)
//  - double-buffered K/V, ONE __syncthreads per tile
//  - balanced pair map (j, 15-j): exactly 34 tiles/CU, same head per CU
// ---------------------------------------------------------------------------

typedef __bf16 bf16_t;
typedef __bf16 bf16x4 __attribute__((ext_vector_type(4)));
typedef __bf16 bf16x8 __attribute__((ext_vector_type(8)));
typedef float f32x4 __attribute__((ext_vector_type(4)));

#define B_DIM 2
#define S_LEN 2048
#define D_DIM 1024
#define H_NUM 16
#define DH 64
#define N_NEU 8
#define R_DIM 256
#define KR_DIM 128
#define ROWS (B_DIM * S_LEN)   // 4096

static __device__ __forceinline__ void gl_lds16(const void* g, void* l)
{
    __builtin_amdgcn_global_load_lds(
        (__attribute__((address_space(1))) void*)(g),
        (__attribute__((address_space(3))) void*)(l), 16, 0, 0);
}

// ---------------------------------------------------------------------------
// Batched transpose-cast: in[z][I][J] f32 -> out[z][J][I] bf16.  block (32,8)
// ---------------------------------------------------------------------------
__global__ __launch_bounds__(256)
void tcast_kernel(const float* __restrict__ in, bf16_t* __restrict__ out, int I, int J)
{
    __shared__ float t[32][33];
    const int bJ = blockIdx.x * 32, bI = blockIdx.y * 32;
    const size_t boff = (size_t)blockIdx.z * I * J;
    const int tx = threadIdx.x, ty = threadIdx.y;
#pragma unroll
    for (int i = 0; i < 4; i++)
        t[ty * 4 + i][tx] = in[boff + (size_t)(bI + ty * 4 + i) * J + bJ + tx];
    __syncthreads();
#pragma unroll
    for (int i = 0; i < 4; i++)
        out[boff + (size_t)(bJ + ty * 4 + i) * I + bI + tx] = (bf16_t)t[tx][ty * 4 + i];
}

// bf16 transpose: in[z][I][J] -> out[z][J][I].  block (32,8)
__global__ __launch_bounds__(256)
void tbf_kernel(const bf16_t* __restrict__ in, bf16_t* __restrict__ out, int I, int J)
{
    __shared__ bf16_t t[32][33];
    const int bJ = blockIdx.x * 32, bI = blockIdx.y * 32;
    const size_t boff = (size_t)blockIdx.z * I * J;
    const int tx = threadIdx.x, ty = threadIdx.y;
#pragma unroll
    for (int i = 0; i < 4; i++)
        t[ty * 4 + i][tx] = in[boff + (size_t)(bI + ty * 4 + i) * J + bJ + tx];
    __syncthreads();
#pragma unroll
    for (int i = 0; i < 4; i++)
        out[boff + (size_t)(bJ + ty * 4 + i) * I + bI + tx] = t[tx][ty * 4 + i];
}

// plain cast fp32 -> bf16 (vectorized by 4)
__global__ __launch_bounds__(256)
void cast_kernel(const float* __restrict__ in, bf16_t* __restrict__ out, int n4)
{
    int i = blockIdx.x * 256 + threadIdx.x;
    if (i < n4) {
        float4 v = ((const float4*)in)[i];
        bf16_t* op = out + (size_t)i * 4;
        op[0] = (bf16_t)v.x; op[1] = (bf16_t)v.y; op[2] = (bf16_t)v.z; op[3] = (bf16_t)v.w;
    }
}

// ---------------------------------------------------------------------------
// LayerNorm over D=1024, one row per block. fp32 in, bf16 out.
// ---------------------------------------------------------------------------
__global__ __launch_bounds__(256)
void ln_kernel(const float* __restrict__ x, const float* __restrict__ g,
               const float* __restrict__ beta, bf16_t* __restrict__ out)
{
    __shared__ float red[4];
    const int row = blockIdx.x;
    const int tid = threadIdx.x;
    float4 v = *(const float4*)&x[(size_t)row * D_DIM + tid * 4];

    float s = v.x + v.y + v.z + v.w;
#pragma unroll
    for (int o = 32; o; o >>= 1) s += __shfl_down(s, o);
    if ((tid & 63) == 0) red[tid >> 6] = s;
    __syncthreads();
    float mean = (red[0] + red[1] + red[2] + red[3]) * (1.f / D_DIM);
    __syncthreads();

    float dx = v.x - mean, dy = v.y - mean, dz = v.z - mean, dw = v.w - mean;
    float q = dx * dx + dy * dy + dz * dz + dw * dw;
#pragma unroll
    for (int o = 32; o; o >>= 1) q += __shfl_down(q, o);
    if ((tid & 63) == 0) red[tid >> 6] = q;
    __syncthreads();
    float var = (red[0] + red[1] + red[2] + red[3]) * (1.f / D_DIM);
    float rstd = rsqrtf(var + 1e-5f);

    float4 gv = *(const float4*)&g[tid * 4];
    float4 bv = *(const float4*)&beta[tid * 4];
    bf16_t* op = out + (size_t)row * D_DIM + tid * 4;
    op[0] = (bf16_t)(dx * rstd * gv.x + bv.x);
    op[1] = (bf16_t)(dy * rstd * gv.y + bv.y);
    op[2] = (bf16_t)(dz * rstd * gv.z + bv.z);
    op[3] = (bf16_t)(dw * rstd * gv.w + bv.w);
}

// ---------------------------------------------------------------------------
// LN2 with fused split-K reduce (bf16 partials) + residual.
// ---------------------------------------------------------------------------
__global__ __launch_bounds__(256)
void ln2x_kernel(const float* __restrict__ x, const bf16_t* __restrict__ P0,
                 const bf16_t* __restrict__ P1, const float* __restrict__ g,
                 const float* __restrict__ beta, float* __restrict__ outf,
                 bf16_t* __restrict__ outn)
{
    __shared__ float red[4];
    const int row = blockIdx.x;
    const int tid = threadIdx.x;
    const size_t base = (size_t)row * D_DIM + tid * 4;
    float4 v  = *(const float4*)&x[base];
    bf16x4 p0 = *(const bf16x4*)&P0[base];
    bf16x4 p1 = *(const bf16x4*)&P1[base];
    v.x += (float)p0[0] + (float)p1[0];
    v.y += (float)p0[1] + (float)p1[1];
    v.z += (float)p0[2] + (float)p1[2];
    v.w += (float)p0[3] + (float)p1[3];
    *(float4*)&outf[base] = v;

    float s = v.x + v.y + v.z + v.w;
#pragma unroll
    for (int o = 32; o; o >>= 1) s += __shfl_down(s, o);
    if ((tid & 63) == 0) red[tid >> 6] = s;
    __syncthreads();
    float mean = (red[0] + red[1] + red[2] + red[3]) * (1.f / D_DIM);
    __syncthreads();

    float dx = v.x - mean, dy = v.y - mean, dz = v.z - mean, dw = v.w - mean;
    float q = dx * dx + dy * dy + dz * dz + dw * dw;
#pragma unroll
    for (int o = 32; o; o >>= 1) q += __shfl_down(q, o);
    if ((tid & 63) == 0) red[tid >> 6] = q;
    __syncthreads();
    float var = (red[0] + red[1] + red[2] + red[3]) * (1.f / D_DIM);
    float rstd = rsqrtf(var + 1e-5f);

    float4 gv = *(const float4*)&g[tid * 4];
    float4 bv = *(const float4*)&beta[tid * 4];
    bf16_t* op = outn + base;
    op[0] = (bf16_t)(dx * rstd * gv.x + bv.x);
    op[1] = (bf16_t)(dy * rstd * gv.y + bv.y);
    op[2] = (bf16_t)(dz * rstd * gv.z + bv.z);
    op[3] = (bf16_t)(dw * rstd * gv.w + bv.w);
}

// ---------------------------------------------------------------------------
// Fused weighted-sum for Q/K/V (1 row/block, 4096 blocks).
// ---------------------------------------------------------------------------
__global__ __launch_bounds__(256)
void wsf_kernel(const bf16_t* __restrict__ y,
                const float* __restrict__ wfQ, const float* __restrict__ wrQ,
                const float* __restrict__ wfK, const float* __restrict__ wrK,
                const float* __restrict__ wfV, const float* __restrict__ wrV,
                bf16_t* __restrict__ sq, bf16_t* __restrict__ sk, bf16_t* __restrict__ sv)
{
    const int r = threadIdx.x;
    const int row = blockIdx.x;
    const bf16_t* yrow = y + (size_t)row * 4096;
    const float* fQ = wfQ + row * N_NEU;
    const float* fK = wfK + row * N_NEU;
    const float* fV = wfV + row * N_NEU;
    float aQ = 0.f, aK = 0.f, aV = 0.f;
#pragma unroll
    for (int n = 0; n < N_NEU; n++) {
        float yq = (float)yrow[n * R_DIM + r];
        float yv = (float)yrow[2048 + n * R_DIM + r];
        aQ += fQ[n] * yq;
        aK += fK[n] * yq;
        aV += fV[n] * yv;
    }
    const float* rQ = wrQ + row * N_NEU;
    const float* rK = wrK + row * N_NEU;
    const float* rV = wrV + row * N_NEU;
    const size_t rb = (size_t)row * 2048;
#pragma unroll
    for (int n = 0; n < N_NEU; n++) {
        sq[rb + n * R_DIM + r] = (bf16_t)(rQ[n] * aQ);
        sk[rb + n * R_DIM + r] = (bf16_t)(rK[n] * aK);
        sv[rb + n * R_DIM + r] = (bf16_t)(rV[n] * aV);
    }
}

// know-path ws with fused split-K reduce (2 rows/block, 2048 blocks).
__global__ __launch_bounds__(256)
void ws2_kernel(const bf16_t* __restrict__ P0, const bf16_t* __restrict__ P1,
                const float* __restrict__ wf, const float* __restrict__ wr,
                bf16_t* __restrict__ sout)
{
    const int lr = threadIdx.x >> 7;
    const int r  = threadIdx.x & 127;
    const int row = blockIdx.x * 2 + lr;
    const size_t rb = (size_t)row * (N_NEU * KR_DIM);
    const float* wfp = wf + row * N_NEU;
    const float* wrp = wr + row * N_NEU;
    float acc = 0.f;
#pragma unroll
    for (int n = 0; n < N_NEU; n++) {
        size_t i = rb + n * KR_DIM + r;
        acc += wfp[n] * ((float)P0[i] + (float)P1[i]);
    }
    bf16_t* srow = sout + rb;
#pragma unroll
    for (int n = 0; n < N_NEU; n++) srow[n * KR_DIM + r] = (bf16_t)(wrp[n] * acc);
}

// ---------------------------------------------------------------------------
// gemm256: C[M,N] = A[M,K] @ Bsel[N,K]^T.  256x128 tile, BK=32, 8 waves,
// single-phase counted-vmcnt 3-buffer pipeline, T2 swizzle (R12-proven).
// EPI=0: bf16 C.  EPI=2: bf16 partial per blockIdx.z (split-K=2).
// ---------------------------------------------------------------------------
template<int EPI>
__global__ __launch_bounds__(512, 2)
void gemm256_kernel(const bf16_t* __restrict__ A, const bf16_t* __restrict__ Bt,
                    const bf16_t* __restrict__ Bt2, int splitMy,
                    void* Cout, int M, int N, int K)
{
    __shared__ bf16_t As[3][256][32];
    __shared__ bf16_t Bs[3][128][32];
    const int tid = threadIdx.x;
    const int l = tid & 63, w = tid >> 6;
    const int wr = w >> 1, wc = w & 1;

    const int nbxy = gridDim.x * gridDim.y;
    int bid = blockIdx.y * gridDim.x + blockIdx.x;
    if ((nbxy & 7) == 0) bid = (bid & 7) * (nbxy >> 3) + (bid >> 3);
    const int bx = bid % gridDim.x, by = bid / gridDim.x;

    const int m0 = by * 256, n0 = bx * 128;
    const bf16_t* Bsel = (by < splitMy) ? Bt : Bt2;

    int kbeg = 0, kend = K;
    if constexpr (EPI == 2) { const int half = K >> 1; kbeg = blockIdx.z * half; kend = kbeg + half; }

    const int strow  = w * 16 + (l >> 2);
    const int scelem = ((((l & 3) * 16) ^ ((strow & 6) << 3)) >> 1);
    const bf16_t* Ag0 = A    + (size_t)(m0 + strow) * K + scelem;
    const bf16_t* Ag1 = A    + (size_t)(m0 + strow + 128) * K + scelem;
    const bf16_t* Bg0 = Bsel + (size_t)(n0 + strow) * K + scelem;

    auto stage = [&](int buf, int k0) {
        char* dA = (char*)&As[buf][0][0] + w * 1024;
        char* dB = (char*)&Bs[buf][0][0] + w * 1024;
        gl_lds16(Ag0 + k0, dA);
        gl_lds16(Ag1 + k0, dA + 8192);
        gl_lds16(Bg0 + k0, dB);
    };

    f32x4 acc[4][4];
    const f32x4 zero = {0.f, 0.f, 0.f, 0.f};
#pragma unroll
    for (int i = 0; i < 4; i++)
#pragma unroll
        for (int j = 0; j < 4; j++) acc[i][j] = zero;

    const int fr  = l & 15;
    const int fkb = (l >> 4) * 16;

    stage(0, kbeg);
    stage(1, kbeg + 32);

    const int nK = (kend - kbeg) >> 5;
    for (int it = 0; it < nK; ++it) {
        if (it + 1 < nK) {
            asm volatile("s_waitcnt vmcnt(3)" ::: "memory");
        } else {
            asm volatile("s_waitcnt vmcnt(0)" ::: "memory");
        }
        __builtin_amdgcn_s_barrier();
        __builtin_amdgcn_sched_barrier(0);

        const int cur = it % 3;
        const char* Ab = (const char*)&As[cur][0][0];
        const char* Bb = (const char*)&Bs[cur][0][0];
        bf16x8 af[4], bv[4];
#pragma unroll
        for (int i = 0; i < 4; i++) {
            const int rowA = wr * 64 + i * 16 + fr;
            af[i] = *(const bf16x8*)(Ab + rowA * 64 + (fkb ^ ((rowA & 6) << 3)));
        }
#pragma unroll
        for (int i = 0; i < 4; i++) {
            const int rowB = wc * 64 + i * 16 + fr;
            bv[i] = *(const bf16x8*)(Bb + rowB * 64 + (fkb ^ ((rowB & 6) << 3)));
        }

        if (it + 2 < nK) stage((it + 2) % 3, kbeg + (it + 2) * 32);

        __builtin_amdgcn_s_setprio(1);
#pragma unroll
        for (int mi = 0; mi < 4; mi++)
#pragma unroll
            for (int ni = 0; ni < 4; ni++)
                acc[mi][ni] = __builtin_amdgcn_mfma_f32_16x16x32_bf16(af[mi], bv[ni], acc[mi][ni], 0, 0, 0);
        __builtin_amdgcn_s_setprio(0);
    }

    const int orow = (l >> 4) * 4;
    const int ocol = l & 15;
#pragma unroll
    for (int mi = 0; mi < 4; mi++)
#pragma unroll
        for (int ni = 0; ni < 4; ni++)
#pragma unroll
            for (int j = 0; j < 4; j++) {
                int row = m0 + wr * 64 + mi * 16 + orow + j;
                int col = n0 + wc * 64 + ni * 16 + ocol;
                size_t idx = (size_t)row * N + col;
                if constexpr (EPI == 0) {
                    ((bf16_t*)Cout)[idx] = (bf16_t)acc[mi][ni][j];
                } else {
                    ((bf16_t*)Cout)[(size_t)blockIdx.z * M * N + idx] = (bf16_t)acc[mi][ni][j];
                }
            }
}

// ---------------------------------------------------------------------------
// Legacy 128x128 GEMM (EPI=1 only: fp32 C = acc + resid).
// ---------------------------------------------------------------------------
template<int EPI>
__global__ __launch_bounds__(256)
void gemm_kernel(const bf16_t* __restrict__ A, const bf16_t* __restrict__ Bt,
                 const bf16_t* __restrict__ Bt2, int splitMy,
                 void* Cout, const float* resid, int M, int N, int K)
{
    __shared__ bf16_t As[3][128][32];
    __shared__ bf16_t Bs[3][128][32];
    const int tid = threadIdx.x;
    const int l = tid & 63, w = tid >> 6;
    const int wr = w >> 1, wc = w & 1;

    const int nbxy = gridDim.x * gridDim.y;
    int bid = blockIdx.y * gridDim.x + blockIdx.x;
    if ((nbxy & 7) == 0) bid = (bid & 7) * (nbxy >> 3) + (bid >> 3);
    const int bx = bid % gridDim.x, by = bid / gridDim.x;

    const int m0 = by * 128, n0 = bx * 128;
    const bf16_t* Bsel = (by < splitMy) ? Bt : Bt2;

    const int kbeg = 0, kend = K;

    const int srow = l >> 2;
    const int scolswz = (((l & 3) * 16) ^ ((srow & 6) << 3)) >> 1;
    const bf16_t* Ag0 = A    + (size_t)(m0 + w * 32 + srow) * K + scolswz;
    const bf16_t* Ag1 = Ag0 + (size_t)16 * K;
    const bf16_t* Bg0 = Bsel + (size_t)(n0 + w * 32 + srow) * K + scolswz;
    const bf16_t* Bg1 = Bg0 + (size_t)16 * K;

    auto stage = [&](int buf, int k0) {
        char* Asb = (char*)&As[buf][0][0] + w * 2048;
        char* Bsb = (char*)&Bs[buf][0][0] + w * 2048;
        gl_lds16(Ag0 + k0, Asb);
        gl_lds16(Ag1 + k0, Asb + 1024);
        gl_lds16(Bg0 + k0, Bsb);
        gl_lds16(Bg1 + k0, Bsb + 1024);
    };

    f32x4 acc[4][4];
    const f32x4 zero = {0.f, 0.f, 0.f, 0.f};
#pragma unroll
    for (int i = 0; i < 4; i++)
#pragma unroll
        for (int j = 0; j < 4; j++) acc[i][j] = zero;

    const int fr = l & 15;
    const int fkb = (l >> 4) * 16;

    stage(0, kbeg);
    stage(1, kbeg + 32);

    const int nK = (kend - kbeg) >> 5;
    for (int it = 0; it < nK; ++it) {
        if (it + 1 < nK) {
            asm volatile("s_waitcnt vmcnt(4)" ::: "memory");
        } else {
            asm volatile("s_waitcnt vmcnt(0)" ::: "memory");
        }
        __builtin_amdgcn_s_barrier();
        __builtin_amdgcn_sched_barrier(0);

        const int cur = it % 3;
        const char* Ab = (const char*)&As[cur][0][0];
        const char* Bb = (const char*)&Bs[cur][0][0];
        bf16x8 af[4], bv[4];
#pragma unroll
        for (int i = 0; i < 4; i++) {
            const int rowA = wr * 64 + i * 16 + fr;
            af[i] = *(const bf16x8*)(Ab + rowA * 64 + (fkb ^ ((rowA & 6) << 3)));
        }
#pragma unroll
        for (int i = 0; i < 4; i++) {
            const int rowB = wc * 64 + i * 16 + fr;
            bv[i] = *(const bf16x8*)(Bb + rowB * 64 + (fkb ^ ((rowB & 6) << 3)));
        }

        if (it + 2 < nK) stage((it + 2) % 3, kbeg + (it + 2) * 32);

        __builtin_amdgcn_s_setprio(1);
#pragma unroll
        for (int mi = 0; mi < 4; mi++)
#pragma unroll
            for (int ni = 0; ni < 4; ni++)
                acc[mi][ni] = __builtin_amdgcn_mfma_f32_16x16x32_bf16(af[mi], bv[ni], acc[mi][ni], 0, 0, 0);
        __builtin_amdgcn_s_setprio(0);
    }

    const int orow = (l >> 4) * 4;
    const int ocol = l & 15;
#pragma unroll
    for (int mi = 0; mi < 4; mi++)
#pragma unroll
        for (int ni = 0; ni < 4; ni++)
#pragma unroll
            for (int j = 0; j < 4; j++) {
                int row = m0 + wr * 64 + mi * 16 + orow + j;
                int col = n0 + wc * 64 + ni * 16 + ocol;
                size_t idx = (size_t)row * N + col;
                ((float*)Cout)[idx] = acc[mi][ni][j] + resid[idx];
            }
}

// ---------------------------------------------------------------------------
// Causal flash attention v2.
// Q/K/O: [B*S][1024] bf16 (head h = cols h*64..+64).  Vt: [B][1024][2048].
// 512 blocks x 512 threads (8 waves); block covers 128 q-rows (16/wave).
// KVBLK=64, double-buffered K/V staged by global_load_lds with T2-swizzled
// global source (LDS dest linear); reads swizzled byte^=((row&7)<<4).
// ONE __syncthreads per tile: barrier (vmcnt0: tile t landed, buf^1 free) ->
// issue t+1 -> compute t.  Balanced map: CU slots (j, 15-j) -> 34 tiles/CU,
// same head per CU.  exp2 softmax, T13 fast-path, MFMA l-sum, diag-only mask.
// LDS: Ks[2][64][64]+Vs[2][64][64]+Ps[8][16][72] = 50.5KB -> 2 blocks/CU,
// 16 waves/CU.
// ---------------------------------------------------------------------------
__global__ __launch_bounds__(512)
void fa_kernel(const bf16_t* __restrict__ Q, const bf16_t* __restrict__ K,
               const bf16_t* __restrict__ Vt, bf16_t* __restrict__ O)
{
    __shared__ bf16_t Ks[2][64][64];
    __shared__ bf16_t Vs[2][64][64];
    __shared__ bf16_t Ps[8][16][72];

    const int tid = threadIdx.x;
    const int l = tid & 63, w = tid >> 6;   // 8 waves

    const int bid  = blockIdx.x;
    const int xcd  = bid & 7;
    const int slot = bid >> 3;          // 0..63
    const int head = slot & 3;
    const int j16  = slot >> 2;         // 0..15
    const int p    = (j16 < 8) ? j16 : (23 - j16);   // pair (j,15-j) per CU
    const int bh   = xcd * 4 + head;
    const int b = bh >> 4, h = bh & 15;
    const int q0 = p * 128;
    const int nt = 2 * p + 2;           // 64-key tiles

    const bf16_t* Qp = Q + (size_t)b * S_LEN * D_DIM + h * DH;
    const bf16_t* Kp = K + (size_t)b * S_LEN * D_DIM + h * DH;
    const bf16_t* Vp = Vt + (size_t)b * D_DIM * S_LEN + (size_t)h * DH * S_LEN;

    const int fr = l & 15, fg = l >> 4, fk = fg * 8;

    // staging: thread t covers tile-row srow = tid>>3, chunk sc = tid&7.
    // LDS dest linear (row*128 + sc*16); global source col pre-swizzled.
    const int srow = tid >> 3;                 // 0..63
    const int scel = 8 * ((tid & 7) ^ (srow & 7));   // swizzled col (elems)
    const bf16_t* Kst = Kp + (size_t)srow * D_DIM + scel;
    const bf16_t* Vst = Vp + (size_t)srow * S_LEN + scel;
    char* KdA = (char*)&Ks[0][w * 8][0];
    char* KdB = (char*)&Ks[1][w * 8][0];
    char* VdA = (char*)&Vs[0][w * 8][0];
    char* VdB = (char*)&Vs[1][w * 8][0];

    bf16x8 ones8;
#pragma unroll
    for (int i = 0; i < 8; i++) ones8[i] = (bf16_t)1.f;

    const f32x4 zero = {0.f, 0.f, 0.f, 0.f};
    const float C_LOG2 = 0.125f * 1.44269504f;   // 1/sqrt(DH) * log2(e)

    // Q fragments (this wave's 16 rows)
    bf16x8 qf[2];
#pragma unroll
    for (int ks = 0; ks < 2; ks++)
        qf[ks] = *(const bf16x8*)(Qp + (size_t)(q0 + w * 16 + fr) * D_DIM + ks * 32 + fk);

    f32x4 o[4];
    f32x4 la = zero;
    float m_r[4];
#pragma unroll
    for (int j = 0; j < 4; j++) { o[j] = zero; m_r[j] = -1e30f; }

    const int wq_hi = q0 + w * 16 + 15;
    const int wq_lo = q0 + w * 16;

    // prologue: stage tile 0 into buf 0
    gl_lds16(Kst, KdA);
    gl_lds16(Vst, VdA);

    for (int t = 0; t < nt; t++) {
        __syncthreads();               // vmcnt(0): tile t landed for ALL waves;
                                       // all reads of buf (t+1)&1 (tile t-1) done
        if (t + 1 < nt) {              // issue tile t+1 into the other buffer
            const size_t kn = (size_t)(t + 1) * 64;
            gl_lds16(Kst + kn * D_DIM, ((t + 1) & 1) ? KdB : KdA);
            gl_lds16(Vst + kn,         ((t + 1) & 1) ? VdB : VdA);
        }

        const int k0 = t * 64;
        if (k0 > wq_hi) continue;      // tile entirely above this wave's rows
        const int cur = t & 1;
        const char* Kb = (const char*)&Ks[cur][0][0];
        const char* Vb = (const char*)&Vs[cur][0][0];
        const int rswz = (fr & 7) << 4;

        // ---- QK^T: 16 q-rows x 64 keys ----
        f32x4 sc[4];
#pragma unroll
        for (int ni = 0; ni < 4; ni++) sc[ni] = zero;
        __builtin_amdgcn_s_setprio(1);
#pragma unroll
        for (int ks = 0; ks < 2; ks++) {
#pragma unroll
            for (int ni = 0; ni < 4; ni++) {
                bf16x8 kf = *(const bf16x8*)(Kb + (ni * 16 + fr) * 128
                                               + ((ks * 64 + fg * 16) ^ rswz));
                sc[ni] = __builtin_amdgcn_mfma_f32_16x16x32_bf16(qf[ks], kf, sc[ni], 0, 0, 0);
            }
        }
        __builtin_amdgcn_s_setprio(0);

        // ---- scale to log2 domain (+ mask only on diagonal-overlap tiles) ----
        float pp[4][4];
        if (k0 + 63 >= wq_lo) {
#pragma unroll
            for (int ni = 0; ni < 4; ni++) {
                const int key = k0 + ni * 16 + fr;
#pragma unroll
                for (int j = 0; j < 4; j++) {
                    const int qg = wq_lo + fg * 4 + j;
                    pp[ni][j] = (key <= qg) ? sc[ni][j] * C_LOG2 : -1e30f;
                }
            }
        } else {
#pragma unroll
            for (int ni = 0; ni < 4; ni++)
#pragma unroll
                for (int j = 0; j < 4; j++)
                    pp[ni][j] = sc[ni][j] * C_LOG2;
        }

        // ---- online softmax, T13 fast-path ----
        float pmax[4];
#pragma unroll
        for (int j = 0; j < 4; j++) {
            float m8 = fmaxf(fmaxf(pp[0][j], pp[1][j]), fmaxf(pp[2][j], pp[3][j]));
            pmax[j] = m8;
        }
        bool need = (pmax[0] > m_r[0] + 8.f) || (pmax[1] > m_r[1] + 8.f) ||
                    (pmax[2] > m_r[2] + 8.f) || (pmax[3] > m_r[3] + 8.f);
        if (__any(need)) {
#pragma unroll
            for (int j = 0; j < 4; j++) {
                float rmax = pmax[j];
#pragma unroll
                for (int d = 1; d < 16; d <<= 1) rmax = fmaxf(rmax, __shfl_xor(rmax, d));
                if (rmax > m_r[j] + 8.f) {
                    float scale = exp2f(m_r[j] - rmax);
                    la[j] *= scale;
#pragma unroll
                    for (int nc = 0; nc < 4; nc++) o[nc][j] *= scale;
                    m_r[j] = rmax;
                }
            }
        }
#pragma unroll
        for (int j = 0; j < 4; j++)
#pragma unroll
            for (int ni = 0; ni < 4; ni++)
                pp[ni][j] = exp2f(pp[ni][j] - m_r[j]);   // <= 2^8

        // ---- P -> A-layout via per-wave LDS bounce ----
#pragma unroll
        for (int ni = 0; ni < 4; ni++)
#pragma unroll
            for (int j = 0; j < 4; j++)
                Ps[w][fg * 4 + j][ni * 16 + fr] = (bf16_t)pp[ni][j];

        // ---- PV + l-sum ----
        __builtin_amdgcn_s_setprio(1);
#pragma unroll
        for (int ks = 0; ks < 2; ks++) {
            bf16x8 pa = *(const bf16x8*)&Ps[w][fr][ks * 32 + fk];
            la = __builtin_amdgcn_mfma_f32_16x16x32_bf16(pa, ones8, la, 0, 0, 0);
#pragma unroll
            for (int nc = 0; nc < 4; nc++) {
                bf16x8 vf = *(const bf16x8*)(Vb + (nc * 16 + fr) * 128
                                               + ((ks * 64 + fg * 16) ^ rswz));
                o[nc] = __builtin_amdgcn_mfma_f32_16x16x32_bf16(pa, vf, o[nc], 0, 0, 0);
            }
        }
        __builtin_amdgcn_s_setprio(0);
    }

    // ---- epilogue ----
#pragma unroll
    for (int j = 0; j < 4; j++) {
        const float inv = 1.f / la[j];
        const int q = wq_lo + fg * 4 + j;
        bf16_t* op = O + (size_t)(b * S_LEN + q) * D_DIM + h * DH;
#pragma unroll
        for (int nc = 0; nc < 4; nc++)
            op[nc * 16 + fr] = (bf16_t)(o[nc][j] * inv);
    }
}

// ---------------------------------------------------------------------------
extern "C" void kernel_launch(void* const* d_in, const int* in_sizes, int n_in,
                              void* d_out, int out_size, void* d_ws, size_t ws_size,
                              hipStream_t stream)
{
    const float* x      = (const float*)d_in[0];
    const float* fqk_wQ = (const float*)d_in[1];
    const float* fqk_wK = (const float*)d_in[2];
    const float* fv_w   = (const float*)d_in[3];
    const float* rqk_wQ = (const float*)d_in[4];
    const float* rqk_wK = (const float*)d_in[5];
    const float* rv_w   = (const float*)d_in[6];
    const float* fkn_w  = (const float*)d_in[7];
    const float* rkn_w  = (const float*)d_in[8];
    const float* f_qk   = (const float*)d_in[9];
    const float* f_v    = (const float*)d_in[10];
    const float* r_qk   = (const float*)d_in[11];
    const float* r_v    = (const float*)d_in[12];
    const float* f_know = (const float*)d_in[13];
    const float* r_know = (const float*)d_in[14];
    const float* W_O    = (const float*)d_in[15];
    const float* ln1g   = (const float*)d_in[16];
    const float* ln1b   = (const float*)d_in[17];
    const float* ln2g   = (const float*)d_in[18];
    const float* ln2b   = (const float*)d_in[19];
    float* out_f = (float*)d_out;
    (void)ws_size; (void)in_sizes; (void)n_in; (void)out_size;

    // ---- workspace layout (reused slots) ----
    char* ws = (char*)d_ws;
    const size_t MB = 1024 * 1024;
    bf16_t* rqkT   = (bf16_t*)(ws + 0 * MB);
    bf16_t* rvT    = (bf16_t*)(ws + 4 * MB);
    bf16_t* rknT   = (bf16_t*)(ws + 8 * MB);
    bf16_t* woB    = (bf16_t*)(ws + 10 * MB);
    bf16_t* fknT   = (bf16_t*)(ws + 12 * MB);
    bf16_t* buf_nx = (bf16_t*)(ws + 14 * MB);   // nx -> Vt -> nx2
    bf16_t* buf_y  = (bf16_t*)(ws + 22 * MB);   // y -> QKV
    char*   buf_s  = ws + 54 * MB;
    bf16_t* fqkT   = (bf16_t*)(buf_s);
    bf16_t* fvT    = (bf16_t*)(buf_s + 4 * MB);
    bf16_t* s_q    = (bf16_t*)(buf_s);
    bf16_t* s_k    = (bf16_t*)(buf_s) + (size_t)4096 * 2048;
    bf16_t* s_v    = (bf16_t*)(buf_s) + (size_t)8192 * 2048;
    bf16_t* attn   = (bf16_t*)(buf_s);
    bf16_t* P0     = (bf16_t*)(buf_s + 16 * MB);
    bf16_t* P0k    = (bf16_t*)(buf_s);
    bf16_t* sk2    = (bf16_t*)(buf_s + 32 * MB);
    bf16_t* Qb     = buf_y;
    bf16_t* Kb     = buf_y + (size_t)4096 * 1024;
    bf16_t* Vb     = buf_y + (size_t)8192 * 1024;
    bf16_t* Vt     = buf_nx;

    const dim3 blk256(256), blk512(512), blkT(32, 8);

    // ---- weight conversion ----
    tcast_kernel<<<dim3(R_DIM / 32, D_DIM / 32, N_NEU), blkT, 0, stream>>>(f_qk, fqkT, D_DIM, R_DIM);
    tcast_kernel<<<dim3(R_DIM / 32, D_DIM / 32, N_NEU), blkT, 0, stream>>>(f_v, fvT, D_DIM, R_DIM);
    tcast_kernel<<<dim3(KR_DIM / 32, D_DIM / 32, N_NEU), blkT, 0, stream>>>(f_know, fknT, D_DIM, KR_DIM);
    tcast_kernel<<<dim3(D_DIM / 32, 2048 / 32, 1), blkT, 0, stream>>>(r_qk, rqkT, 2048, D_DIM);
    tcast_kernel<<<dim3(D_DIM / 32, 2048 / 32, 1), blkT, 0, stream>>>(r_v, rvT, 2048, D_DIM);
    tcast_kernel<<<dim3(D_DIM / 32, 1024 / 32, 1), blkT, 0, stream>>>(r_know, rknT, 1024, D_DIM);
    cast_kernel<<<dim3(1024 * 1024 / 4 / 256), blk256, 0, stream>>>(W_O, woB, 1024 * 1024 / 4);

    // ---- LN1 ----
    ln_kernel<<<dim3(ROWS), blk256, 0, stream>>>(x, ln1g, ln1b, buf_nx);

    // ---- fused feature GEMM (512 blocks) ----
    gemm256_kernel<0><<<dim3(32, 16), blk512, 0, stream>>>(buf_nx, fqkT, fqkT, 1 << 30, buf_y, 4096, 4096, 1024);

    // ---- fused weighted sums (4096 blocks) ----
    wsf_kernel<<<dim3(ROWS), blk256, 0, stream>>>(buf_y, fqk_wQ, rqk_wQ, fqk_wK, rqk_wK, fv_w, rv_w, s_q, s_k, s_v);

    // ---- grouped restore GEMM: QKV[12288][1024] (384 blocks, B-select) ----
    gemm256_kernel<0><<<dim3(8, 48), blk512, 0, stream>>>((bf16_t*)buf_s, rqkT, rvT, 32, buf_y, 12288, 1024, 2048);

    // ---- V -> Vt ----
    tbf_kernel<<<dim3(D_DIM / 32, S_LEN / 32, B_DIM), blkT, 0, stream>>>(Vb, Vt, S_LEN, D_DIM);

    // ---- attention (512 blocks x 8 waves, Q-tile 128, dbuf gl_lds) ----
    fa_kernel<<<dim3(512), blk512, 0, stream>>>(Qb, Kb, Vt, attn);

    // ---- W_O split-K=2: bf16 partials (256 blocks) ----
    gemm256_kernel<2><<<dim3(8, 16, 2), blk512, 0, stream>>>(attn, woB, woB, 1 << 30, P0, 4096, 1024, 1024);

    // ---- LN2 fused ----
    ln2x_kernel<<<dim3(ROWS), blk256, 0, stream>>>(x, P0, P0 + (size_t)4096 * 1024, ln2g, ln2b, out_f, buf_nx);

    // ---- know feature split-K=2: bf16 partials (256 blocks) ----
    gemm256_kernel<2><<<dim3(8, 16, 2), blk512, 0, stream>>>(buf_nx, fknT, fknT, 1 << 30, P0k, 4096, 1024, 1024);

    // ---- know ws (2048 blocks) ----
    ws2_kernel<<<dim3(ROWS / 2), blk256, 0, stream>>>(P0k, P0k + (size_t)4096 * 1024, fkn_w, rkn_w, sk2);

    // ---- out = sk2 @ rknT^T + x2 -> d_out ----
    gemm_kernel<1><<<dim3(8, 32), blk256, 0, stream>>>(sk2, rknT, rknT, 1 << 30, d_out, out_f, 4096, 1024, 1024);
}

// Round 17
// 272.340 us; speedup vs baseline: 1.1576x; 1.0200x over previous
//
#include <hip/hip_runtime.h>
#include <hip/hip_bf16.h>

// ---------------------------------------------------------------------------
// DAWN block on MI355X.  Round 17 = R16 + gemm256sq for the two big GEMMs:
// 256x256 block, per-wave 128x64 output (af[8]xbv[4]: 32 MFMA per 12 LDS
// reads vs 16 per 8 -> +33% FLOP/LDS-cycle; kernel was LDS-read bound at
// MfmaUtil 34%).  Same proven single-phase counted-vmcnt 3-buffer schedule.
// ---------------------------------------------------------------------------

typedef __bf16 bf16_t;
typedef __bf16 bf16x4 __attribute__((ext_vector_type(4)));
typedef __bf16 bf16x8 __attribute__((ext_vector_type(8)));
typedef float f32x4 __attribute__((ext_vector_type(4)));

#define B_DIM 2
#define S_LEN 2048
#define D_DIM 1024
#define H_NUM 16
#define DH 64
#define N_NEU 8
#define R_DIM 256
#define KR_DIM 128
#define ROWS (B_DIM * S_LEN)   // 4096

static __device__ __forceinline__ void gl_lds16(const void* g, void* l)
{
    __builtin_amdgcn_global_load_lds(
        (__attribute__((address_space(1))) void*)(g),
        (__attribute__((address_space(3))) void*)(l), 16, 0, 0);
}

// ---------------------------------------------------------------------------
// Batched transpose-cast: in[z][I][J] f32 -> out[z][J][I] bf16.  block (32,8)
// ---------------------------------------------------------------------------
__global__ __launch_bounds__(256)
void tcast_kernel(const float* __restrict__ in, bf16_t* __restrict__ out, int I, int J)
{
    __shared__ float t[32][33];
    const int bJ = blockIdx.x * 32, bI = blockIdx.y * 32;
    const size_t boff = (size_t)blockIdx.z * I * J;
    const int tx = threadIdx.x, ty = threadIdx.y;
#pragma unroll
    for (int i = 0; i < 4; i++)
        t[ty * 4 + i][tx] = in[boff + (size_t)(bI + ty * 4 + i) * J + bJ + tx];
    __syncthreads();
#pragma unroll
    for (int i = 0; i < 4; i++)
        out[boff + (size_t)(bJ + ty * 4 + i) * I + bI + tx] = (bf16_t)t[tx][ty * 4 + i];
}

// bf16 transpose: in[z][I][J] -> out[z][J][I].  block (32,8)
__global__ __launch_bounds__(256)
void tbf_kernel(const bf16_t* __restrict__ in, bf16_t* __restrict__ out, int I, int J)
{
    __shared__ bf16_t t[32][33];
    const int bJ = blockIdx.x * 32, bI = blockIdx.y * 32;
    const size_t boff = (size_t)blockIdx.z * I * J;
    const int tx = threadIdx.x, ty = threadIdx.y;
#pragma unroll
    for (int i = 0; i < 4; i++)
        t[ty * 4 + i][tx] = in[boff + (size_t)(bI + ty * 4 + i) * J + bJ + tx];
    __syncthreads();
#pragma unroll
    for (int i = 0; i < 4; i++)
        out[boff + (size_t)(bJ + ty * 4 + i) * I + bI + tx] = t[tx][ty * 4 + i];
}

// plain cast fp32 -> bf16 (vectorized by 4)
__global__ __launch_bounds__(256)
void cast_kernel(const float* __restrict__ in, bf16_t* __restrict__ out, int n4)
{
    int i = blockIdx.x * 256 + threadIdx.x;
    if (i < n4) {
        float4 v = ((const float4*)in)[i];
        bf16_t* op = out + (size_t)i * 4;
        op[0] = (bf16_t)v.x; op[1] = (bf16_t)v.y; op[2] = (bf16_t)v.z; op[3] = (bf16_t)v.w;
    }
}

// ---------------------------------------------------------------------------
// LayerNorm over D=1024, one row per block. fp32 in, bf16 out.
// ---------------------------------------------------------------------------
__global__ __launch_bounds__(256)
void ln_kernel(const float* __restrict__ x, const float* __restrict__ g,
               const float* __restrict__ beta, bf16_t* __restrict__ out)
{
    __shared__ float red[4];
    const int row = blockIdx.x;
    const int tid = threadIdx.x;
    float4 v = *(const float4*)&x[(size_t)row * D_DIM + tid * 4];

    float s = v.x + v.y + v.z + v.w;
#pragma unroll
    for (int o = 32; o; o >>= 1) s += __shfl_down(s, o);
    if ((tid & 63) == 0) red[tid >> 6] = s;
    __syncthreads();
    float mean = (red[0] + red[1] + red[2] + red[3]) * (1.f / D_DIM);
    __syncthreads();

    float dx = v.x - mean, dy = v.y - mean, dz = v.z - mean, dw = v.w - mean;
    float q = dx * dx + dy * dy + dz * dz + dw * dw;
#pragma unroll
    for (int o = 32; o; o >>= 1) q += __shfl_down(q, o);
    if ((tid & 63) == 0) red[tid >> 6] = q;
    __syncthreads();
    float var = (red[0] + red[1] + red[2] + red[3]) * (1.f / D_DIM);
    float rstd = rsqrtf(var + 1e-5f);

    float4 gv = *(const float4*)&g[tid * 4];
    float4 bv = *(const float4*)&beta[tid * 4];
    bf16_t* op = out + (size_t)row * D_DIM + tid * 4;
    op[0] = (bf16_t)(dx * rstd * gv.x + bv.x);
    op[1] = (bf16_t)(dy * rstd * gv.y + bv.y);
    op[2] = (bf16_t)(dz * rstd * gv.z + bv.z);
    op[3] = (bf16_t)(dw * rstd * gv.w + bv.w);
}

// ---------------------------------------------------------------------------
// LN2 with fused split-K reduce (bf16 partials) + residual.
// ---------------------------------------------------------------------------
__global__ __launch_bounds__(256)
void ln2x_kernel(const float* __restrict__ x, const bf16_t* __restrict__ P0,
                 const bf16_t* __restrict__ P1, const float* __restrict__ g,
                 const float* __restrict__ beta, float* __restrict__ outf,
                 bf16_t* __restrict__ outn)
{
    __shared__ float red[4];
    const int row = blockIdx.x;
    const int tid = threadIdx.x;
    const size_t base = (size_t)row * D_DIM + tid * 4;
    float4 v  = *(const float4*)&x[base];
    bf16x4 p0 = *(const bf16x4*)&P0[base];
    bf16x4 p1 = *(const bf16x4*)&P1[base];
    v.x += (float)p0[0] + (float)p1[0];
    v.y += (float)p0[1] + (float)p1[1];
    v.z += (float)p0[2] + (float)p1[2];
    v.w += (float)p0[3] + (float)p1[3];
    *(float4*)&outf[base] = v;

    float s = v.x + v.y + v.z + v.w;
#pragma unroll
    for (int o = 32; o; o >>= 1) s += __shfl_down(s, o);
    if ((tid & 63) == 0) red[tid >> 6] = s;
    __syncthreads();
    float mean = (red[0] + red[1] + red[2] + red[3]) * (1.f / D_DIM);
    __syncthreads();

    float dx = v.x - mean, dy = v.y - mean, dz = v.z - mean, dw = v.w - mean;
    float q = dx * dx + dy * dy + dz * dz + dw * dw;
#pragma unroll
    for (int o = 32; o; o >>= 1) q += __shfl_down(q, o);
    if ((tid & 63) == 0) red[tid >> 6] = q;
    __syncthreads();
    float var = (red[0] + red[1] + red[2] + red[3]) * (1.f / D_DIM);
    float rstd = rsqrtf(var + 1e-5f);

    float4 gv = *(const float4*)&g[tid * 4];
    float4 bv = *(const float4*)&beta[tid * 4];
    bf16_t* op = outn + base;
    op[0] = (bf16_t)(dx * rstd * gv.x + bv.x);
    op[1] = (bf16_t)(dy * rstd * gv.y + bv.y);
    op[2] = (bf16_t)(dz * rstd * gv.z + bv.z);
    op[3] = (bf16_t)(dw * rstd * gv.w + bv.w);
}

// ---------------------------------------------------------------------------
// Fused weighted-sum for Q/K/V (1 row/block, 4096 blocks).
// ---------------------------------------------------------------------------
__global__ __launch_bounds__(256)
void wsf_kernel(const bf16_t* __restrict__ y,
                const float* __restrict__ wfQ, const float* __restrict__ wrQ,
                const float* __restrict__ wfK, const float* __restrict__ wrK,
                const float* __restrict__ wfV, const float* __restrict__ wrV,
                bf16_t* __restrict__ sq, bf16_t* __restrict__ sk, bf16_t* __restrict__ sv)
{
    const int r = threadIdx.x;
    const int row = blockIdx.x;
    const bf16_t* yrow = y + (size_t)row * 4096;
    const float* fQ = wfQ + row * N_NEU;
    const float* fK = wfK + row * N_NEU;
    const float* fV = wfV + row * N_NEU;
    float aQ = 0.f, aK = 0.f, aV = 0.f;
#pragma unroll
    for (int n = 0; n < N_NEU; n++) {
        float yq = (float)yrow[n * R_DIM + r];
        float yv = (float)yrow[2048 + n * R_DIM + r];
        aQ += fQ[n] * yq;
        aK += fK[n] * yq;
        aV += fV[n] * yv;
    }
    const float* rQ = wrQ + row * N_NEU;
    const float* rK = wrK + row * N_NEU;
    const float* rV = wrV + row * N_NEU;
    const size_t rb = (size_t)row * 2048;
#pragma unroll
    for (int n = 0; n < N_NEU; n++) {
        sq[rb + n * R_DIM + r] = (bf16_t)(rQ[n] * aQ);
        sk[rb + n * R_DIM + r] = (bf16_t)(rK[n] * aK);
        sv[rb + n * R_DIM + r] = (bf16_t)(rV[n] * aV);
    }
}

// know-path ws with fused split-K reduce (2 rows/block, 2048 blocks).
__global__ __launch_bounds__(256)
void ws2_kernel(const bf16_t* __restrict__ P0, const bf16_t* __restrict__ P1,
                const float* __restrict__ wf, const float* __restrict__ wr,
                bf16_t* __restrict__ sout)
{
    const int lr = threadIdx.x >> 7;
    const int r  = threadIdx.x & 127;
    const int row = blockIdx.x * 2 + lr;
    const size_t rb = (size_t)row * (N_NEU * KR_DIM);
    const float* wfp = wf + row * N_NEU;
    const float* wrp = wr + row * N_NEU;
    float acc = 0.f;
#pragma unroll
    for (int n = 0; n < N_NEU; n++) {
        size_t i = rb + n * KR_DIM + r;
        acc += wfp[n] * ((float)P0[i] + (float)P1[i]);
    }
    bf16_t* srow = sout + rb;
#pragma unroll
    for (int n = 0; n < N_NEU; n++) srow[n * KR_DIM + r] = (bf16_t)(wrp[n] * acc);
}

// ---------------------------------------------------------------------------
// gemm256sq: C[M,N] = A[M,K] @ Bsel[N,K]^T.  256x256 block, BK=32, 8 waves
// (2M x 4N), per-wave output 128x64 (af[8] x bv[4] -> 32 MFMA / 12 LDS reads).
// Single-phase counted-vmcnt 3-buffer pipeline (R12-proven), T2 swizzle.
// LDS 96KB -> 1 block/CU, 8 waves.  bf16 C only.
// splitMy in units of 256-row M-tiles (B-select for grouped GEMM).
// ---------------------------------------------------------------------------
__global__ __launch_bounds__(512, 1)
void gemm256sq_kernel(const bf16_t* __restrict__ A, const bf16_t* __restrict__ Bt,
                      const bf16_t* __restrict__ Bt2, int splitMy,
                      bf16_t* __restrict__ Cout, int M, int N, int K)
{
    __shared__ bf16_t As[3][256][32];   // 48 KB
    __shared__ bf16_t Bs[3][256][32];   // 48 KB
    const int tid = threadIdx.x;        // 0..511
    const int l = tid & 63, w = tid >> 6;
    const int wr = w >> 2;              // 0..1 (M half)
    const int wc = w & 3;               // 0..3 (N quarter)

    // XCD-chunked swizzle (bijective: grids are multiples of 8)
    const int nbxy = gridDim.x * gridDim.y;
    int bid = blockIdx.y * gridDim.x + blockIdx.x;
    if ((nbxy & 7) == 0) bid = (bid & 7) * (nbxy >> 3) + (bid >> 3);
    const int bx = bid % gridDim.x, by = bid / gridDim.x;

    const int m0 = by * 256, n0 = bx * 256;
    const bf16_t* Bsel = (by < splitMy) ? Bt : Bt2;

    // staging: wave w covers rows w*16+(l>>2) and +128 of BOTH tiles.
    const int strow  = w * 16 + (l >> 2);
    const int scelem = ((((l & 3) * 16) ^ ((strow & 6) << 3)) >> 1);
    const bf16_t* Ag0 = A    + (size_t)(m0 + strow) * K + scelem;
    const bf16_t* Ag1 = A    + (size_t)(m0 + strow + 128) * K + scelem;
    const bf16_t* Bg0 = Bsel + (size_t)(n0 + strow) * K + scelem;
    const bf16_t* Bg1 = Bsel + (size_t)(n0 + strow + 128) * K + scelem;

    auto stage = [&](int buf, int k0) {
        char* dA = (char*)&As[buf][0][0] + w * 1024;
        char* dB = (char*)&Bs[buf][0][0] + w * 1024;
        gl_lds16(Ag0 + k0, dA);
        gl_lds16(Ag1 + k0, dA + 8192);
        gl_lds16(Bg0 + k0, dB);
        gl_lds16(Bg1 + k0, dB + 8192);
    };

    f32x4 acc[8][4];
    const f32x4 zero = {0.f, 0.f, 0.f, 0.f};
#pragma unroll
    for (int i = 0; i < 8; i++)
#pragma unroll
        for (int j = 0; j < 4; j++) acc[i][j] = zero;

    const int fr  = l & 15;
    const int fkb = (l >> 4) * 16;

    stage(0, 0);
    stage(1, 32);

    const int nK = K >> 5;
    for (int it = 0; it < nK; ++it) {
        if (it + 1 < nK) {
            asm volatile("s_waitcnt vmcnt(4)" ::: "memory");   // tile it landed
        } else {
            asm volatile("s_waitcnt vmcnt(0)" ::: "memory");
        }
        __builtin_amdgcn_s_barrier();
        __builtin_amdgcn_sched_barrier(0);

        const int cur = it % 3;
        const char* Ab = (const char*)&As[cur][0][0];
        const char* Bb = (const char*)&Bs[cur][0][0];
        bf16x8 af[8], bv[4];
#pragma unroll
        for (int i = 0; i < 8; i++) {
            const int rowA = wr * 128 + i * 16 + fr;
            af[i] = *(const bf16x8*)(Ab + rowA * 64 + (fkb ^ ((rowA & 6) << 3)));
        }
#pragma unroll
        for (int i = 0; i < 4; i++) {
            const int rowB = wc * 64 + i * 16 + fr;
            bv[i] = *(const bf16x8*)(Bb + rowB * 64 + (fkb ^ ((rowB & 6) << 3)));
        }

        if (it + 2 < nK) stage((it + 2) % 3, (it + 2) * 32);

        __builtin_amdgcn_s_setprio(1);
#pragma unroll
        for (int mi = 0; mi < 8; mi++)
#pragma unroll
            for (int ni = 0; ni < 4; ni++)
                acc[mi][ni] = __builtin_amdgcn_mfma_f32_16x16x32_bf16(af[mi], bv[ni], acc[mi][ni], 0, 0, 0);
        __builtin_amdgcn_s_setprio(0);
    }

    const int orow = (l >> 4) * 4;
    const int ocol = l & 15;
#pragma unroll
    for (int mi = 0; mi < 8; mi++)
#pragma unroll
        for (int ni = 0; ni < 4; ni++)
#pragma unroll
            for (int j = 0; j < 4; j++) {
                int row = m0 + wr * 128 + mi * 16 + orow + j;
                int col = n0 + wc * 64 + ni * 16 + ocol;
                Cout[(size_t)row * N + col] = (bf16_t)acc[mi][ni][j];
            }
}

// ---------------------------------------------------------------------------
// gemm256: 256x128 tile, EPI=2 split-K (bf16 partials).  R12-proven.
// ---------------------------------------------------------------------------
template<int EPI>
__global__ __launch_bounds__(512, 2)
void gemm256_kernel(const bf16_t* __restrict__ A, const bf16_t* __restrict__ Bt,
                    const bf16_t* __restrict__ Bt2, int splitMy,
                    void* Cout, int M, int N, int K)
{
    __shared__ bf16_t As[3][256][32];
    __shared__ bf16_t Bs[3][128][32];
    const int tid = threadIdx.x;
    const int l = tid & 63, w = tid >> 6;
    const int wr = w >> 1, wc = w & 1;

    const int nbxy = gridDim.x * gridDim.y;
    int bid = blockIdx.y * gridDim.x + blockIdx.x;
    if ((nbxy & 7) == 0) bid = (bid & 7) * (nbxy >> 3) + (bid >> 3);
    const int bx = bid % gridDim.x, by = bid / gridDim.x;

    const int m0 = by * 256, n0 = bx * 128;
    const bf16_t* Bsel = (by < splitMy) ? Bt : Bt2;

    int kbeg = 0, kend = K;
    if constexpr (EPI == 2) { const int half = K >> 1; kbeg = blockIdx.z * half; kend = kbeg + half; }

    const int strow  = w * 16 + (l >> 2);
    const int scelem = ((((l & 3) * 16) ^ ((strow & 6) << 3)) >> 1);
    const bf16_t* Ag0 = A    + (size_t)(m0 + strow) * K + scelem;
    const bf16_t* Ag1 = A    + (size_t)(m0 + strow + 128) * K + scelem;
    const bf16_t* Bg0 = Bsel + (size_t)(n0 + strow) * K + scelem;

    auto stage = [&](int buf, int k0) {
        char* dA = (char*)&As[buf][0][0] + w * 1024;
        char* dB = (char*)&Bs[buf][0][0] + w * 1024;
        gl_lds16(Ag0 + k0, dA);
        gl_lds16(Ag1 + k0, dA + 8192);
        gl_lds16(Bg0 + k0, dB);
    };

    f32x4 acc[4][4];
    const f32x4 zero = {0.f, 0.f, 0.f, 0.f};
#pragma unroll
    for (int i = 0; i < 4; i++)
#pragma unroll
        for (int j = 0; j < 4; j++) acc[i][j] = zero;

    const int fr  = l & 15;
    const int fkb = (l >> 4) * 16;

    stage(0, kbeg);
    stage(1, kbeg + 32);

    const int nK = (kend - kbeg) >> 5;
    for (int it = 0; it < nK; ++it) {
        if (it + 1 < nK) {
            asm volatile("s_waitcnt vmcnt(3)" ::: "memory");
        } else {
            asm volatile("s_waitcnt vmcnt(0)" ::: "memory");
        }
        __builtin_amdgcn_s_barrier();
        __builtin_amdgcn_sched_barrier(0);

        const int cur = it % 3;
        const char* Ab = (const char*)&As[cur][0][0];
        const char* Bb = (const char*)&Bs[cur][0][0];
        bf16x8 af[4], bv[4];
#pragma unroll
        for (int i = 0; i < 4; i++) {
            const int rowA = wr * 64 + i * 16 + fr;
            af[i] = *(const bf16x8*)(Ab + rowA * 64 + (fkb ^ ((rowA & 6) << 3)));
        }
#pragma unroll
        for (int i = 0; i < 4; i++) {
            const int rowB = wc * 64 + i * 16 + fr;
            bv[i] = *(const bf16x8*)(Bb + rowB * 64 + (fkb ^ ((rowB & 6) << 3)));
        }

        if (it + 2 < nK) stage((it + 2) % 3, kbeg + (it + 2) * 32);

        __builtin_amdgcn_s_setprio(1);
#pragma unroll
        for (int mi = 0; mi < 4; mi++)
#pragma unroll
            for (int ni = 0; ni < 4; ni++)
                acc[mi][ni] = __builtin_amdgcn_mfma_f32_16x16x32_bf16(af[mi], bv[ni], acc[mi][ni], 0, 0, 0);
        __builtin_amdgcn_s_setprio(0);
    }

    const int orow = (l >> 4) * 4;
    const int ocol = l & 15;
#pragma unroll
    for (int mi = 0; mi < 4; mi++)
#pragma unroll
        for (int ni = 0; ni < 4; ni++)
#pragma unroll
            for (int j = 0; j < 4; j++) {
                int row = m0 + wr * 64 + mi * 16 + orow + j;
                int col = n0 + wc * 64 + ni * 16 + ocol;
                size_t idx = (size_t)row * N + col;
                if constexpr (EPI == 0) {
                    ((bf16_t*)Cout)[idx] = (bf16_t)acc[mi][ni][j];
                } else {
                    ((bf16_t*)Cout)[(size_t)blockIdx.z * M * N + idx] = (bf16_t)acc[mi][ni][j];
                }
            }
}

// ---------------------------------------------------------------------------
// Legacy 128x128 GEMM (EPI=1 only: fp32 C = acc + resid).
// ---------------------------------------------------------------------------
template<int EPI>
__global__ __launch_bounds__(256)
void gemm_kernel(const bf16_t* __restrict__ A, const bf16_t* __restrict__ Bt,
                 const bf16_t* __restrict__ Bt2, int splitMy,
                 void* Cout, const float* resid, int M, int N, int K)
{
    __shared__ bf16_t As[3][128][32];
    __shared__ bf16_t Bs[3][128][32];
    const int tid = threadIdx.x;
    const int l = tid & 63, w = tid >> 6;
    const int wr = w >> 1, wc = w & 1;

    const int nbxy = gridDim.x * gridDim.y;
    int bid = blockIdx.y * gridDim.x + blockIdx.x;
    if ((nbxy & 7) == 0) bid = (bid & 7) * (nbxy >> 3) + (bid >> 3);
    const int bx = bid % gridDim.x, by = bid / gridDim.x;

    const int m0 = by * 128, n0 = bx * 128;
    const bf16_t* Bsel = (by < splitMy) ? Bt : Bt2;

    const int kbeg = 0, kend = K;

    const int srow = l >> 2;
    const int scolswz = (((l & 3) * 16) ^ ((srow & 6) << 3)) >> 1;
    const bf16_t* Ag0 = A    + (size_t)(m0 + w * 32 + srow) * K + scolswz;
    const bf16_t* Ag1 = Ag0 + (size_t)16 * K;
    const bf16_t* Bg0 = Bsel + (size_t)(n0 + w * 32 + srow) * K + scolswz;
    const bf16_t* Bg1 = Bg0 + (size_t)16 * K;

    auto stage = [&](int buf, int k0) {
        char* Asb = (char*)&As[buf][0][0] + w * 2048;
        char* Bsb = (char*)&Bs[buf][0][0] + w * 2048;
        gl_lds16(Ag0 + k0, Asb);
        gl_lds16(Ag1 + k0, Asb + 1024);
        gl_lds16(Bg0 + k0, Bsb);
        gl_lds16(Bg1 + k0, Bsb + 1024);
    };

    f32x4 acc[4][4];
    const f32x4 zero = {0.f, 0.f, 0.f, 0.f};
#pragma unroll
    for (int i = 0; i < 4; i++)
#pragma unroll
        for (int j = 0; j < 4; j++) acc[i][j] = zero;

    const int fr = l & 15;
    const int fkb = (l >> 4) * 16;

    stage(0, kbeg);
    stage(1, kbeg + 32);

    const int nK = (kend - kbeg) >> 5;
    for (int it = 0; it < nK; ++it) {
        if (it + 1 < nK) {
            asm volatile("s_waitcnt vmcnt(4)" ::: "memory");
        } else {
            asm volatile("s_waitcnt vmcnt(0)" ::: "memory");
        }
        __builtin_amdgcn_s_barrier();
        __builtin_amdgcn_sched_barrier(0);

        const int cur = it % 3;
        const char* Ab = (const char*)&As[cur][0][0];
        const char* Bb = (const char*)&Bs[cur][0][0];
        bf16x8 af[4], bv[4];
#pragma unroll
        for (int i = 0; i < 4; i++) {
            const int rowA = wr * 64 + i * 16 + fr;
            af[i] = *(const bf16x8*)(Ab + rowA * 64 + (fkb ^ ((rowA & 6) << 3)));
        }
#pragma unroll
        for (int i = 0; i < 4; i++) {
            const int rowB = wc * 64 + i * 16 + fr;
            bv[i] = *(const bf16x8*)(Bb + rowB * 64 + (fkb ^ ((rowB & 6) << 3)));
        }

        if (it + 2 < nK) stage((it + 2) % 3, kbeg + (it + 2) * 32);

        __builtin_amdgcn_s_setprio(1);
#pragma unroll
        for (int mi = 0; mi < 4; mi++)
#pragma unroll
            for (int ni = 0; ni < 4; ni++)
                acc[mi][ni] = __builtin_amdgcn_mfma_f32_16x16x32_bf16(af[mi], bv[ni], acc[mi][ni], 0, 0, 0);
        __builtin_amdgcn_s_setprio(0);
    }

    const int orow = (l >> 4) * 4;
    const int ocol = l & 15;
#pragma unroll
    for (int mi = 0; mi < 4; mi++)
#pragma unroll
        for (int ni = 0; ni < 4; ni++)
#pragma unroll
            for (int j = 0; j < 4; j++) {
                int row = m0 + wr * 64 + mi * 16 + orow + j;
                int col = n0 + wc * 64 + ni * 16 + ocol;
                size_t idx = (size_t)row * N + col;
                ((float*)Cout)[idx] = acc[mi][ni][j] + resid[idx];
            }
}

// ---------------------------------------------------------------------------
// Causal flash attention v2 (R16, unchanged).
// ---------------------------------------------------------------------------
__global__ __launch_bounds__(512)
void fa_kernel(const bf16_t* __restrict__ Q, const bf16_t* __restrict__ K,
               const bf16_t* __restrict__ Vt, bf16_t* __restrict__ O)
{
    __shared__ bf16_t Ks[2][64][64];
    __shared__ bf16_t Vs[2][64][64];
    __shared__ bf16_t Ps[8][16][72];

    const int tid = threadIdx.x;
    const int l = tid & 63, w = tid >> 6;   // 8 waves

    const int bid  = blockIdx.x;
    const int xcd  = bid & 7;
    const int slot = bid >> 3;          // 0..63
    const int head = slot & 3;
    const int j16  = slot >> 2;         // 0..15
    const int p    = (j16 < 8) ? j16 : (23 - j16);   // pair (j,15-j) per CU
    const int bh   = xcd * 4 + head;
    const int b = bh >> 4, h = bh & 15;
    const int q0 = p * 128;
    const int nt = 2 * p + 2;           // 64-key tiles

    const bf16_t* Qp = Q + (size_t)b * S_LEN * D_DIM + h * DH;
    const bf16_t* Kp = K + (size_t)b * S_LEN * D_DIM + h * DH;
    const bf16_t* Vp = Vt + (size_t)b * D_DIM * S_LEN + (size_t)h * DH * S_LEN;

    const int fr = l & 15, fg = l >> 4, fk = fg * 8;

    const int srow = tid >> 3;                 // 0..63
    const int scel = 8 * ((tid & 7) ^ (srow & 7));   // swizzled col (elems)
    const bf16_t* Kst = Kp + (size_t)srow * D_DIM + scel;
    const bf16_t* Vst = Vp + (size_t)srow * S_LEN + scel;
    char* KdA = (char*)&Ks[0][w * 8][0];
    char* KdB = (char*)&Ks[1][w * 8][0];
    char* VdA = (char*)&Vs[0][w * 8][0];
    char* VdB = (char*)&Vs[1][w * 8][0];

    bf16x8 ones8;
#pragma unroll
    for (int i = 0; i < 8; i++) ones8[i] = (bf16_t)1.f;

    const f32x4 zero = {0.f, 0.f, 0.f, 0.f};
    const float C_LOG2 = 0.125f * 1.44269504f;   // 1/sqrt(DH) * log2(e)

    bf16x8 qf[2];
#pragma unroll
    for (int ks = 0; ks < 2; ks++)
        qf[ks] = *(const bf16x8*)(Qp + (size_t)(q0 + w * 16 + fr) * D_DIM + ks * 32 + fk);

    f32x4 o[4];
    f32x4 la = zero;
    float m_r[4];
#pragma unroll
    for (int j = 0; j < 4; j++) { o[j] = zero; m_r[j] = -1e30f; }

    const int wq_hi = q0 + w * 16 + 15;
    const int wq_lo = q0 + w * 16;

    gl_lds16(Kst, KdA);
    gl_lds16(Vst, VdA);

    for (int t = 0; t < nt; t++) {
        __syncthreads();
        if (t + 1 < nt) {
            const size_t kn = (size_t)(t + 1) * 64;
            gl_lds16(Kst + kn * D_DIM, ((t + 1) & 1) ? KdB : KdA);
            gl_lds16(Vst + kn,         ((t + 1) & 1) ? VdB : VdA);
        }

        const int k0 = t * 64;
        if (k0 > wq_hi) continue;
        const int cur = t & 1;
        const char* Kb = (const char*)&Ks[cur][0][0];
        const char* Vb = (const char*)&Vs[cur][0][0];
        const int rswz = (fr & 7) << 4;

        f32x4 sc[4];
#pragma unroll
        for (int ni = 0; ni < 4; ni++) sc[ni] = zero;
        __builtin_amdgcn_s_setprio(1);
#pragma unroll
        for (int ks = 0; ks < 2; ks++) {
#pragma unroll
            for (int ni = 0; ni < 4; ni++) {
                bf16x8 kf = *(const bf16x8*)(Kb + (ni * 16 + fr) * 128
                                               + ((ks * 64 + fg * 16) ^ rswz));
                sc[ni] = __builtin_amdgcn_mfma_f32_16x16x32_bf16(qf[ks], kf, sc[ni], 0, 0, 0);
            }
        }
        __builtin_amdgcn_s_setprio(0);

        float pp[4][4];
        if (k0 + 63 >= wq_lo) {
#pragma unroll
            for (int ni = 0; ni < 4; ni++) {
                const int key = k0 + ni * 16 + fr;
#pragma unroll
                for (int j = 0; j < 4; j++) {
                    const int qg = wq_lo + fg * 4 + j;
                    pp[ni][j] = (key <= qg) ? sc[ni][j] * C_LOG2 : -1e30f;
                }
            }
        } else {
#pragma unroll
            for (int ni = 0; ni < 4; ni++)
#pragma unroll
                for (int j = 0; j < 4; j++)
                    pp[ni][j] = sc[ni][j] * C_LOG2;
        }

        float pmax[4];
#pragma unroll
        for (int j = 0; j < 4; j++)
            pmax[j] = fmaxf(fmaxf(pp[0][j], pp[1][j]), fmaxf(pp[2][j], pp[3][j]));
        bool need = (pmax[0] > m_r[0] + 8.f) || (pmax[1] > m_r[1] + 8.f) ||
                    (pmax[2] > m_r[2] + 8.f) || (pmax[3] > m_r[3] + 8.f);
        if (__any(need)) {
#pragma unroll
            for (int j = 0; j < 4; j++) {
                float rmax = pmax[j];
#pragma unroll
                for (int d = 1; d < 16; d <<= 1) rmax = fmaxf(rmax, __shfl_xor(rmax, d));
                if (rmax > m_r[j] + 8.f) {
                    float scale = exp2f(m_r[j] - rmax);
                    la[j] *= scale;
#pragma unroll
                    for (int nc = 0; nc < 4; nc++) o[nc][j] *= scale;
                    m_r[j] = rmax;
                }
            }
        }
#pragma unroll
        for (int j = 0; j < 4; j++)
#pragma unroll
            for (int ni = 0; ni < 4; ni++)
                pp[ni][j] = exp2f(pp[ni][j] - m_r[j]);

#pragma unroll
        for (int ni = 0; ni < 4; ni++)
#pragma unroll
            for (int j = 0; j < 4; j++)
                Ps[w][fg * 4 + j][ni * 16 + fr] = (bf16_t)pp[ni][j];

        __builtin_amdgcn_s_setprio(1);
#pragma unroll
        for (int ks = 0; ks < 2; ks++) {
            bf16x8 pa = *(const bf16x8*)&Ps[w][fr][ks * 32 + fk];
            la = __builtin_amdgcn_mfma_f32_16x16x32_bf16(pa, ones8, la, 0, 0, 0);
#pragma unroll
            for (int nc = 0; nc < 4; nc++) {
                bf16x8 vf = *(const bf16x8*)(Vb + (nc * 16 + fr) * 128
                                               + ((ks * 64 + fg * 16) ^ rswz));
                o[nc] = __builtin_amdgcn_mfma_f32_16x16x32_bf16(pa, vf, o[nc], 0, 0, 0);
            }
        }
        __builtin_amdgcn_s_setprio(0);
    }

#pragma unroll
    for (int j = 0; j < 4; j++) {
        const float inv = 1.f / la[j];
        const int q = wq_lo + fg * 4 + j;
        bf16_t* op = O + (size_t)(b * S_LEN + q) * D_DIM + h * DH;
#pragma unroll
        for (int nc = 0; nc < 4; nc++)
            op[nc * 16 + fr] = (bf16_t)(o[nc][j] * inv);
    }
}

// ---------------------------------------------------------------------------
extern "C" void kernel_launch(void* const* d_in, const int* in_sizes, int n_in,
                              void* d_out, int out_size, void* d_ws, size_t ws_size,
                              hipStream_t stream)
{
    const float* x      = (const float*)d_in[0];
    const float* fqk_wQ = (const float*)d_in[1];
    const float* fqk_wK = (const float*)d_in[2];
    const float* fv_w   = (const float*)d_in[3];
    const float* rqk_wQ = (const float*)d_in[4];
    const float* rqk_wK = (const float*)d_in[5];
    const float* rv_w   = (const float*)d_in[6];
    const float* fkn_w  = (const float*)d_in[7];
    const float* rkn_w  = (const float*)d_in[8];
    const float* f_qk   = (const float*)d_in[9];
    const float* f_v    = (const float*)d_in[10];
    const float* r_qk   = (const float*)d_in[11];
    const float* r_v    = (const float*)d_in[12];
    const float* f_know = (const float*)d_in[13];
    const float* r_know = (const float*)d_in[14];
    const float* W_O    = (const float*)d_in[15];
    const float* ln1g   = (const float*)d_in[16];
    const float* ln1b   = (const float*)d_in[17];
    const float* ln2g   = (const float*)d_in[18];
    const float* ln2b   = (const float*)d_in[19];
    float* out_f = (float*)d_out;
    (void)ws_size; (void)in_sizes; (void)n_in; (void)out_size;

    // ---- workspace layout (reused slots) ----
    char* ws = (char*)d_ws;
    const size_t MB = 1024 * 1024;
    bf16_t* rqkT   = (bf16_t*)(ws + 0 * MB);
    bf16_t* rvT    = (bf16_t*)(ws + 4 * MB);
    bf16_t* rknT   = (bf16_t*)(ws + 8 * MB);
    bf16_t* woB    = (bf16_t*)(ws + 10 * MB);
    bf16_t* fknT   = (bf16_t*)(ws + 12 * MB);
    bf16_t* buf_nx = (bf16_t*)(ws + 14 * MB);   // nx -> Vt -> nx2
    bf16_t* buf_y  = (bf16_t*)(ws + 22 * MB);   // y -> QKV
    char*   buf_s  = ws + 54 * MB;
    bf16_t* fqkT   = (bf16_t*)(buf_s);
    bf16_t* fvT    = (bf16_t*)(buf_s + 4 * MB);
    bf16_t* s_q    = (bf16_t*)(buf_s);
    bf16_t* s_k    = (bf16_t*)(buf_s) + (size_t)4096 * 2048;
    bf16_t* s_v    = (bf16_t*)(buf_s) + (size_t)8192 * 2048;
    bf16_t* attn   = (bf16_t*)(buf_s);
    bf16_t* P0     = (bf16_t*)(buf_s + 16 * MB);
    bf16_t* P0k    = (bf16_t*)(buf_s);
    bf16_t* sk2    = (bf16_t*)(buf_s + 32 * MB);
    bf16_t* Qb     = buf_y;
    bf16_t* Kb     = buf_y + (size_t)4096 * 1024;
    bf16_t* Vb     = buf_y + (size_t)8192 * 1024;
    bf16_t* Vt     = buf_nx;

    const dim3 blk256(256), blk512(512), blkT(32, 8);

    // ---- weight conversion ----
    tcast_kernel<<<dim3(R_DIM / 32, D_DIM / 32, N_NEU), blkT, 0, stream>>>(f_qk, fqkT, D_DIM, R_DIM);
    tcast_kernel<<<dim3(R_DIM / 32, D_DIM / 32, N_NEU), blkT, 0, stream>>>(f_v, fvT, D_DIM, R_DIM);
    tcast_kernel<<<dim3(KR_DIM / 32, D_DIM / 32, N_NEU), blkT, 0, stream>>>(f_know, fknT, D_DIM, KR_DIM);
    tcast_kernel<<<dim3(D_DIM / 32, 2048 / 32, 1), blkT, 0, stream>>>(r_qk, rqkT, 2048, D_DIM);
    tcast_kernel<<<dim3(D_DIM / 32, 2048 / 32, 1), blkT, 0, stream>>>(r_v, rvT, 2048, D_DIM);
    tcast_kernel<<<dim3(D_DIM / 32, 1024 / 32, 1), blkT, 0, stream>>>(r_know, rknT, 1024, D_DIM);
    cast_kernel<<<dim3(1024 * 1024 / 4 / 256), blk256, 0, stream>>>(W_O, woB, 1024 * 1024 / 4);

    // ---- LN1 ----
    ln_kernel<<<dim3(ROWS), blk256, 0, stream>>>(x, ln1g, ln1b, buf_nx);

    // ---- fused feature GEMM: y[4096][4096] (256 blocks, 256x256 tile) ----
    gemm256sq_kernel<<<dim3(16, 16), blk512, 0, stream>>>(buf_nx, fqkT, fqkT, 1 << 30, buf_y, 4096, 4096, 1024);

    // ---- fused weighted sums (4096 blocks) ----
    wsf_kernel<<<dim3(ROWS), blk256, 0, stream>>>(buf_y, fqk_wQ, rqk_wQ, fqk_wK, rqk_wK, fv_w, rv_w, s_q, s_k, s_v);

    // ---- grouped restore GEMM: QKV[12288][1024] (192 blocks, 256x256 tile) ----
    gemm256sq_kernel<<<dim3(4, 48), blk512, 0, stream>>>((bf16_t*)buf_s, rqkT, rvT, 32, buf_y, 12288, 1024, 2048);

    // ---- V -> Vt ----
    tbf_kernel<<<dim3(D_DIM / 32, S_LEN / 32, B_DIM), blkT, 0, stream>>>(Vb, Vt, S_LEN, D_DIM);

    // ---- attention (512 blocks x 8 waves, Q-tile 128, dbuf gl_lds) ----
    fa_kernel<<<dim3(512), blk512, 0, stream>>>(Qb, Kb, Vt, attn);

    // ---- W_O split-K=2: bf16 partials (256 blocks) ----
    gemm256_kernel<2><<<dim3(8, 16, 2), blk512, 0, stream>>>(attn, woB, woB, 1 << 30, P0, 4096, 1024, 1024);

    // ---- LN2 fused ----
    ln2x_kernel<<<dim3(ROWS), blk256, 0, stream>>>(x, P0, P0 + (size_t)4096 * 1024, ln2g, ln2b, out_f, buf_nx);

    // ---- know feature split-K=2: bf16 partials (256 blocks) ----
    gemm256_kernel<2><<<dim3(8, 16, 2), blk512, 0, stream>>>(buf_nx, fknT, fknT, 1 << 30, P0k, 4096, 1024, 1024);

    // ---- know ws (2048 blocks) ----
    ws2_kernel<<<dim3(ROWS / 2), blk256, 0, stream>>>(P0k, P0k + (size_t)4096 * 1024, fkn_w, rkn_w, sk2);

    // ---- out = sk2 @ rknT^T + x2 -> d_out ----
    gemm_kernel<1><<<dim3(8, 32), blk256, 0, stream>>>(sk2, rknT, rknT, 1 << 30, d_out, out_f, 4096, 1024, 1024);
}